// Round 1
// baseline (5440.092 us; speedup 1.0000x reference)
//
#include <hip/hip_runtime.h>

#define EPSQ 1e-8f

static constexpr int  Bn = 8, Cc = 128, Hh = 128, Ww = 128, HW = Hh * Ww; // 16384
static constexpr int  C4 = 512, CO = 256;
static constexpr long NX   = (long)Bn * Cc * HW;   // 16,777,216
static constexpr long NP1  = (long)Bn * C4 * HW;   // 67,108,864
static constexpr long NOUT = (long)Bn * CO * HW;   // 33,554,432

// ---------------- reductions ----------------

__device__ __forceinline__ float block_reduce_max(float v) {
    __shared__ float sm[8];
    #pragma unroll
    for (int off = 32; off; off >>= 1) v = fmaxf(v, __shfl_down(v, off));
    int lane = threadIdx.x & 63, wid = threadIdx.x >> 6;
    int nw = (blockDim.x + 63) >> 6;
    if (lane == 0) sm[wid] = v;
    __syncthreads();
    float r = sm[0];
    for (int i = 1; i < nw; i++) r = fmaxf(r, sm[i]);
    __syncthreads();
    return r;
}

__device__ __forceinline__ void block_max_atomic(float v, unsigned* slot) {
    #pragma unroll
    for (int off = 32; off; off >>= 1) v = fmaxf(v, __shfl_down(v, off));
    __shared__ float sm[8];
    int lane = threadIdx.x & 63, wid = threadIdx.x >> 6;
    if (lane == 0) sm[wid] = v;
    __syncthreads();
    if (threadIdx.x == 0) {
        float m = sm[0];
        int nw = (blockDim.x + 63) >> 6;
        for (int i = 1; i < nw; i++) m = fmaxf(m, sm[i]);
        // guarded atomic: values only grow; skip if current already >= m
        if (m > __uint_as_float(*(volatile unsigned*)slot))
            atomicMax(slot, __float_as_uint(m));
    }
    __syncthreads();
}

// ---------------- absmax over big tensor ----------------

__global__ void absmax_kernel(const float* __restrict__ x, long n, unsigned* slot) {
    long i = (long)blockIdx.x * blockDim.x + threadIdx.x;
    long stride = (long)gridDim.x * blockDim.x;
    const float4* x4 = (const float4*)x;
    long n4 = n >> 2;
    float m = 0.f;
    for (long j = i; j < n4; j += stride) {
        float4 v = x4[j];
        m = fmaxf(m, fmaxf(fmaxf(fabsf(v.x), fabsf(v.y)), fmaxf(fabsf(v.z), fabsf(v.w))));
    }
    block_max_atomic(m, slot);
}

// ---------------- weight fake-quant (one block per tensor) ----------------

struct QW { const float* src; float* dst; int n; };

__global__ void quant_weights_kernel(QW q0, QW q1, QW q2, QW q3, QW q4,
                                     QW q5, QW q6, QW q7, QW q8, QW q9) {
    QW q;
    switch (blockIdx.x) {
        case 0: q = q0; break; case 1: q = q1; break; case 2: q = q2; break;
        case 3: q = q3; break; case 4: q = q4; break; case 5: q = q5; break;
        case 6: q = q6; break; case 7: q = q7; break; case 8: q = q8; break;
        default: q = q9; break;
    }
    float m = 0.f;
    for (int i = threadIdx.x; i < q.n; i += blockDim.x) m = fmaxf(m, fabsf(q.src[i]));
    float mall = block_reduce_max(m);
    float s = fmaxf(mall, EPSQ) / 127.f;
    for (int i = threadIdx.x; i < q.n; i += blockDim.x) {
        float v = rintf(q.src[i] / s);
        v = fminf(fmaxf(v, -127.f), 127.f);
        q.dst[i] = v * s;
    }
}

// ---------------- depthwise 3x3 (pad 1), raw input, quantized weights ----------------

__global__ void dwconv_kernel(const float* __restrict__ in, const float* __restrict__ wq,
                              const float* __restrict__ bq, float* __restrict__ out,
                              unsigned* mslot) {
    int bc = blockIdx.x;              // b*C + c
    int c  = bc & (Cc - 1);
    float w[9];
    #pragma unroll
    for (int k = 0; k < 9; k++) w[k] = wq[c * 9 + k];
    float bias = bq[c];
    const float* src = in + (long)bc * HW;
    float* dst = out + (long)bc * HW;
    int j  = threadIdx.x & (Ww - 1);
    int r2 = threadIdx.x >> 7;        // 0..1
    float mm = 0.f;
    #pragma unroll
    for (int rr = 0; rr < 4; rr++) {
        int i = blockIdx.y * 8 + rr * 2 + r2;
        float acc = 0.f;
        #pragma unroll
        for (int di = 0; di < 3; di++) {
            int ii = i + di - 1;
            if (ii < 0 || ii >= Hh) continue;
            #pragma unroll
            for (int dj = 0; dj < 3; dj++) {
                int jj = j + dj - 1;
                if (jj < 0 || jj >= Ww) continue;
                acc = fmaf(w[di * 3 + dj], src[ii * Ww + jj], acc);
            }
        }
        acc += bias;
        dst[i * Ww + j] = acc;
        mm = fmaxf(mm, fmaxf(acc, 0.f));   // max of relu for quant_relu scale
    }
    block_max_atomic(mm, mslot);
}

// ---------------- residual combine: fq(quant_relu(t)) + fq(x) ----------------

__global__ void residual_kernel(const float4* __restrict__ t, const float4* __restrict__ xin,
                                float4* __restrict__ r, const unsigned* __restrict__ scal,
                                int mReluIdx, int mXIdx, unsigned* mOut) {
    float s1  = fmaxf(__uint_as_float(scal[mReluIdx]), EPSQ) / 255.f;
    float mh  = 255.f * s1;                         // max of quant_relu output
    float s1b = fmaxf(mh, EPSQ) / 127.f;
    float sx  = fmaxf(__uint_as_float(scal[mXIdx]), EPSQ) / 127.f;
    long i0 = (long)blockIdx.x * blockDim.x + threadIdx.x;
    long str = (long)gridDim.x * blockDim.x;
    long n4 = NX >> 2;
    float mm = 0.f;
    for (long i = i0; i < n4; i += str) {
        float4 tv = t[i];
        float4 xv = xin[i];
        float o[4];
        float tc[4] = {tv.x, tv.y, tv.z, tv.w};
        float xc[4] = {xv.x, xv.y, xv.z, xv.w};
        #pragma unroll
        for (int k = 0; k < 4; k++) {
            float h  = fminf(rintf(fmaxf(tc[k], 0.f) / s1), 255.f) * s1;      // quant_relu
            float hq = fminf(fmaxf(rintf(h / s1b), -127.f), 127.f) * s1b;     // fq_sym(h)
            float xq = fminf(fmaxf(rintf(xc[k] / sx), -127.f), 127.f) * sx;   // fq_sym(x)
            o[k] = hq + xq;
            mm = fmaxf(mm, fabsf(o[k]));
        }
        float4 ov = {o[0], o[1], o[2], o[3]};
        r[i] = ov;
    }
    if (mOut) block_max_atomic(mm, mOut);
    // (if mOut==nullptr, skip; all threads agree -> no divergence hazard)
}

// ---------------- pointwise conv (1x1) as GEMM, stores relu, tracks max ----------------
// split-buffer addressing: b<4 -> Lo, b>=4 -> Hi (Hi may be null = unsplit)

template <int K, int OP>
__global__ void pwconv_kernel(const float* __restrict__ inLo, const float* __restrict__ inHi,
                              const float* __restrict__ wq, const float* __restrict__ bq,
                              float* __restrict__ outLo, float* __restrict__ outHi,
                              int O, unsigned* mslot) {
    int hw = blockIdx.x * blockDim.x + threadIdx.x;
    int o0 = blockIdx.y * OP;
    int b  = blockIdx.z;
    const float* src = ((inHi != nullptr && b >= 4) ? (inHi + (long)(b - 4) * K * HW)
                                                    : (inLo + (long)b * K * HW)) + hw;
    float acc[OP];
    #pragma unroll
    for (int k = 0; k < OP; k++) acc[k] = 0.f;
    for (int c = 0; c < K; c++) {
        float xv = src[(long)c * HW];
        #pragma unroll
        for (int k = 0; k < OP; k++) acc[k] = fmaf(wq[(o0 + k) * K + c], xv, acc[k]);
    }
    float* dst; int bb;
    if (outHi != nullptr && b >= 4) { dst = outHi; bb = b - 4; } else { dst = outLo; bb = b; }
    float mm = 0.f;
    #pragma unroll
    for (int k = 0; k < OP; k++) {
        float v = fmaxf(acc[k] + bq[o0 + k], 0.f);
        mm = fmaxf(mm, v);
        dst[((long)(bb * O + o0 + k)) * HW + hw] = v;
    }
    block_max_atomic(mm, mslot);
}

// ---------------- 3x3 conv C->CO (pad 1), quantized input, stores relu ----------------

__global__ void conv3x3_kernel(const float* __restrict__ in, const float* __restrict__ wq,
                               const float* __restrict__ bq, float* __restrict__ out,
                               unsigned* mslot) {
    int hw = blockIdx.x * blockDim.x + threadIdx.x;
    int i = hw >> 7, j = hw & 127;
    int o0 = blockIdx.y * 8, b = blockIdx.z;
    const float* src = in + (long)b * Cc * HW;
    float acc[8];
    #pragma unroll
    for (int k = 0; k < 8; k++) acc[k] = 0.f;
    for (int c = 0; c < Cc; c++) {
        const float* s = src + (long)c * HW;
        #pragma unroll
        for (int di = 0; di < 3; di++) {
            int ii = i + di - 1;
            if (ii < 0 || ii >= Hh) continue;
            #pragma unroll
            for (int dj = 0; dj < 3; dj++) {
                int jj = j + dj - 1;
                if (jj < 0 || jj >= Ww) continue;
                float xv = s[ii * Ww + jj];
                #pragma unroll
                for (int k = 0; k < 8; k++)
                    acc[k] = fmaf(wq[((o0 + k) * Cc + c) * 9 + di * 3 + dj], xv, acc[k]);
            }
        }
    }
    float mm = 0.f;
    #pragma unroll
    for (int k = 0; k < 8; k++) {
        float v = fmaxf(acc[k] + bq[o0 + k], 0.f);
        mm = fmaxf(mm, v);
        out[((long)(b * CO + o0 + k)) * HW + hw] = v;
    }
    block_max_atomic(mm, mslot);
}

// ---------------- in-place quant of a relu'd tensor (255 levels) ----------------

__global__ void quant_inplace_kernel(float4* __restrict__ p, long n4,
                                     const unsigned* __restrict__ scal, int idx) {
    float s = fmaxf(__uint_as_float(scal[idx]), EPSQ) / 255.f;
    long i0 = (long)blockIdx.x * blockDim.x + threadIdx.x;
    long str = (long)gridDim.x * blockDim.x;
    for (long i = i0; i < n4; i += str) {
        float4 v = p[i];
        v.x = fminf(rintf(v.x / s), 255.f) * s;
        v.y = fminf(rintf(v.y / s), 255.f) * s;
        v.z = fminf(rintf(v.z / s), 255.f) * s;
        v.w = fminf(rintf(v.w / s), 255.f) * s;
        p[i] = v;
    }
}

// ---------------- launch ----------------

extern "C" void kernel_launch(void* const* d_in, const int* in_sizes, int n_in,
                              void* d_out, int out_size, void* d_ws, size_t ws_size,
                              hipStream_t stream) {
    (void)in_sizes; (void)n_in; (void)out_size; (void)ws_size;
    const float* x     = (const float*)d_in[0];
    const float* dw1_w = (const float*)d_in[1];
    const float* dw1_b = (const float*)d_in[2];
    const float* dw2_w = (const float*)d_in[3];
    const float* dw2_b = (const float*)d_in[4];
    const float* pw1_w = (const float*)d_in[5];
    const float* pw1_b = (const float*)d_in[6];
    const float* pw2_w = (const float*)d_in[7];
    const float* pw2_b = (const float*)d_in[8];
    const float* up_w  = (const float*)d_in[9];
    const float* up_b  = (const float*)d_in[10];
    float* out = (float*)d_out;
    float* ws  = (float*)d_ws;

    // ws layout (floats): A(16.7M) | B(16.7M) | Chalf(33.5M) | wq(429440) | scal(16)
    float* Abuf  = ws;
    float* Bbuf  = ws + NX;
    float* Chalf = ws + 2 * NX;
    float* wqb   = ws + 2 * NX + NP1 / 2;
    float* wq_dw1 = wqb;           float* bq_dw1 = wqb + 1152;
    float* wq_dw2 = wqb + 1280;    float* bq_dw2 = wqb + 2432;
    float* wq_pw1 = wqb + 2560;    float* bq_pw1 = wqb + 68096;
    float* wq_pw2 = wqb + 68608;   float* bq_pw2 = wqb + 134144;
    float* wq_up  = wqb + 134272;  float* bq_up  = wqb + 429184;
    unsigned* scal = (unsigned*)(wqb + 429440);
    // slots: 0=SX  1=M1(dw1 relu)  2=MR1(|r1|)  3=M2(dw2 relu)  4=M3(pw1)  5=M4(pw2)  6=M5(up)

    (void)hipMemsetAsync(scal, 0, 16 * sizeof(unsigned), stream);

    QW q0{dw1_w, wq_dw1, 1152}, q1{dw1_b, bq_dw1, 128},
       q2{dw2_w, wq_dw2, 1152}, q3{dw2_b, bq_dw2, 128},
       q4{pw1_w, wq_pw1, 65536}, q5{pw1_b, bq_pw1, 512},
       q6{pw2_w, wq_pw2, 65536}, q7{pw2_b, bq_pw2, 128},
       q8{up_w,  wq_up, 294912}, q9{up_b,  bq_up, 256};
    quant_weights_kernel<<<10, 256, 0, stream>>>(q0, q1, q2, q3, q4, q5, q6, q7, q8, q9);

    absmax_kernel<<<2048, 256, 0, stream>>>(x, NX, scal + 0);

    // residual block 1
    dwconv_kernel<<<dim3(Bn * Cc, Hh / 8), 256, 0, stream>>>(x, wq_dw1, bq_dw1, Abuf, scal + 1);
    residual_kernel<<<4096, 256, 0, stream>>>((const float4*)Abuf, (const float4*)x,
                                              (float4*)Bbuf, scal, 1, 0, scal + 2);
    // residual block 2 (in-place on B)
    dwconv_kernel<<<dim3(Bn * Cc, Hh / 8), 256, 0, stream>>>(Bbuf, wq_dw2, bq_dw2, Abuf, scal + 3);
    residual_kernel<<<4096, 256, 0, stream>>>((const float4*)Abuf, (const float4*)Bbuf,
                                              (float4*)Bbuf, scal, 3, 2, nullptr);

    // pw1: 128 -> 512, relu stored split across d_out (b<4) and Chalf (b>=4)
    pwconv_kernel<128, 8><<<dim3(HW / 256, C4 / 8, Bn), 256, 0, stream>>>(
        Bbuf, nullptr, wq_pw1, bq_pw1, out, Chalf, C4, scal + 4);
    quant_inplace_kernel<<<4096, 256, 0, stream>>>((float4*)out,   NOUT / 4, scal, 4);
    quant_inplace_kernel<<<4096, 256, 0, stream>>>((float4*)Chalf, NOUT / 4, scal, 4);

    // pw2: 512 -> 128, into A
    pwconv_kernel<512, 8><<<dim3(HW / 256, Cc / 8, Bn), 256, 0, stream>>>(
        out, Chalf, wq_pw2, bq_pw2, Abuf, nullptr, Cc, scal + 5);
    quant_inplace_kernel<<<4096, 256, 0, stream>>>((float4*)Abuf, NX / 4, scal, 5);

    // up: 3x3, 128 -> 256, into d_out
    conv3x3_kernel<<<dim3(HW / 256, CO / 8, Bn), 256, 0, stream>>>(Abuf, wq_up, bq_up, out, scal + 6);
    quant_inplace_kernel<<<4096, 256, 0, stream>>>((float4*)out, NOUT / 4, scal, 6);
}

// Round 2
// 1990.439 us; speedup vs baseline: 2.7331x; 2.7331x over previous
//
#include <hip/hip_runtime.h>

#define EPSQ 1e-8f

typedef unsigned short u16;
typedef __attribute__((ext_vector_type(8))) short short8v;
typedef __attribute__((ext_vector_type(8))) unsigned short ushort8v;
typedef __attribute__((ext_vector_type(4))) unsigned short ushort4v;
typedef __attribute__((ext_vector_type(4))) float f32x4;
typedef __attribute__((ext_vector_type(4))) unsigned int uint4v;

static constexpr int  Bn = 8, Cc = 128, Hh = 128, Ww = 128, HW = Hh * Ww; // 16384
static constexpr int  C4 = 512, CO = 256;
static constexpr long NX   = (long)Bn * Cc * HW;   // 16,777,216
static constexpr long NOUT = (long)Bn * CO * HW;   // 33,554,432

#define MFMA16(a,b,c) __builtin_amdgcn_mfma_f32_16x16x32_bf16(a,b,c,0,0,0)

__device__ __forceinline__ u16 f2bf(float f) { return (u16)(__float_as_uint(f) >> 16); } // exact for small ints
__device__ __forceinline__ float ubits(unsigned u) { return __uint_as_float(u); }

// ---------------- reductions ----------------

__device__ __forceinline__ float block_reduce_max(float v) {
    __shared__ float sm[8];
    #pragma unroll
    for (int off = 32; off; off >>= 1) v = fmaxf(v, __shfl_down(v, off));
    int lane = threadIdx.x & 63, wid = threadIdx.x >> 6;
    int nw = (blockDim.x + 63) >> 6;
    if (lane == 0) sm[wid] = v;
    __syncthreads();
    float r = sm[0];
    for (int i = 1; i < nw; i++) r = fmaxf(r, sm[i]);
    __syncthreads();
    return r;
}

__device__ __forceinline__ void block_max_atomic(float v, unsigned* slot) {
    #pragma unroll
    for (int off = 32; off; off >>= 1) v = fmaxf(v, __shfl_down(v, off));
    __shared__ float sm[8];
    int lane = threadIdx.x & 63, wid = threadIdx.x >> 6;
    if (lane == 0) sm[wid] = v;
    __syncthreads();
    if (threadIdx.x == 0) {
        float m = sm[0];
        int nw = (blockDim.x + 63) >> 6;
        for (int i = 1; i < nw; i++) m = fmaxf(m, sm[i]);
        if (m > __uint_as_float(*(volatile unsigned*)slot))
            atomicMax(slot, __float_as_uint(m));
    }
    __syncthreads();
}

// version with caller-provided LDS scratch (for kernels whose static LDS is at the 64KB cap)
__device__ __forceinline__ void block_max_atomic2(float v, unsigned* slot, float* sm) {
    #pragma unroll
    for (int off = 32; off; off >>= 1) v = fmaxf(v, __shfl_down(v, off));
    int lane = threadIdx.x & 63, wid = threadIdx.x >> 6;
    __syncthreads();                       // LDS may be in use by other waves
    if (lane == 0) sm[wid] = v;
    __syncthreads();
    if (threadIdx.x == 0) {
        float m = sm[0];
        int nw = (blockDim.x + 63) >> 6;
        for (int i = 1; i < nw; i++) m = fmaxf(m, sm[i]);
        if (m > __uint_as_float(*(volatile unsigned*)slot))
            atomicMax(slot, __float_as_uint(m));
    }
}

// ---------------- absmax over big tensor ----------------

__global__ void absmax_kernel(const float* __restrict__ x, long n, unsigned* slot) {
    long i = (long)blockIdx.x * blockDim.x + threadIdx.x;
    long stride = (long)gridDim.x * blockDim.x;
    const float4* x4 = (const float4*)x;
    long n4 = n >> 2;
    float m = 0.f;
    for (long j = i; j < n4; j += stride) {
        float4 v = x4[j];
        m = fmaxf(m, fmaxf(fmaxf(fabsf(v.x), fabsf(v.y)), fmaxf(fabsf(v.z), fabsf(v.w))));
    }
    block_max_atomic(m, slot);
}

// ---------------- weight fake-quant ----------------
// mode 0: write fp32 dequant to dstF. mode 1: write bf16 codes to dstC (same layout).
// mode 2: write bf16 codes transposed OIHW[o][c][t] -> [o][t][c] (3x3, C=128).
struct QW { const float* src; float* dstF; u16* dstC; int n; int mode; int slot; };

__global__ void quant_weights_kernel(QW q0, QW q1, QW q2, QW q3, QW q4,
                                     QW q5, QW q6, QW q7, QW q8, QW q9,
                                     unsigned* __restrict__ scal) {
    QW q;
    switch (blockIdx.x) {
        case 0: q = q0; break; case 1: q = q1; break; case 2: q = q2; break;
        case 3: q = q3; break; case 4: q = q4; break; case 5: q = q5; break;
        case 6: q = q6; break; case 7: q = q7; break; case 8: q = q8; break;
        default: q = q9; break;
    }
    float m = 0.f;
    for (int i = threadIdx.x; i < q.n; i += blockDim.x) m = fmaxf(m, fabsf(q.src[i]));
    float mall = block_reduce_max(m);
    float s = fmaxf(mall, EPSQ) / 127.f;
    if (q.mode != 0 && threadIdx.x == 0) scal[q.slot] = __float_as_uint(s);
    for (int i = threadIdx.x; i < q.n; i += blockDim.x) {
        float v = fminf(fmaxf(rintf(q.src[i] / s), -127.f), 127.f);
        if (q.mode == 0) q.dstF[i] = v * s;
        else if (q.mode == 1) q.dstC[i] = f2bf(v);
        else {
            int o = i / 1152, rem = i % 1152, c = rem / 9, t = rem % 9;
            q.dstC[(o * 9 + t) * 128 + c] = f2bf(v);
        }
    }
}

// ---------------- depthwise 3x3 (pad 1), fp32 ----------------

__global__ void dwconv_kernel(const float* __restrict__ in, const float* __restrict__ wq,
                              const float* __restrict__ bq, float* __restrict__ out,
                              unsigned* mslot) {
    int bc = blockIdx.x;              // b*C + c
    int c  = bc & (Cc - 1);
    float w[9];
    #pragma unroll
    for (int k = 0; k < 9; k++) w[k] = wq[c * 9 + k];
    float bias = bq[c];
    const float* src = in + (long)bc * HW;
    float* dst = out + (long)bc * HW;
    int j  = threadIdx.x & (Ww - 1);
    int r2 = threadIdx.x >> 7;        // 0..1
    float mm = 0.f;
    #pragma unroll
    for (int rr = 0; rr < 4; rr++) {
        int i = blockIdx.y * 8 + rr * 2 + r2;
        float acc = 0.f;
        #pragma unroll
        for (int di = 0; di < 3; di++) {
            int ii = i + di - 1;
            if (ii < 0 || ii >= Hh) continue;
            #pragma unroll
            for (int dj = 0; dj < 3; dj++) {
                int jj = j + dj - 1;
                if (jj < 0 || jj >= Ww) continue;
                acc = fmaf(w[di * 3 + dj], src[ii * Ww + jj], acc);
            }
        }
        acc += bias;
        dst[i * Ww + j] = acc;
        mm = fmaxf(mm, fmaxf(acc, 0.f));
    }
    block_max_atomic(mm, mslot);
}

// ---------------- residual 1: r = fq(quant_relu(t)) + fq(x), fp32 out + max ----------------

__global__ void residual_kernel(const float4* __restrict__ t, const float4* __restrict__ xin,
                                float4* __restrict__ r, const unsigned* __restrict__ scal,
                                int mReluIdx, int mXIdx, unsigned* mOut) {
    float s1  = fmaxf(__uint_as_float(scal[mReluIdx]), EPSQ) / 255.f;
    float mh  = 255.f * s1;
    float s1b = fmaxf(mh, EPSQ) / 127.f;
    float sx  = fmaxf(__uint_as_float(scal[mXIdx]), EPSQ) / 127.f;
    long i0 = (long)blockIdx.x * blockDim.x + threadIdx.x;
    long str = (long)gridDim.x * blockDim.x;
    long n4 = NX >> 2;
    float mm = 0.f;
    for (long i = i0; i < n4; i += str) {
        float4 tv = t[i];
        float4 xv = xin[i];
        float o[4];
        float tc[4] = {tv.x, tv.y, tv.z, tv.w};
        float xc[4] = {xv.x, xv.y, xv.z, xv.w};
        #pragma unroll
        for (int k = 0; k < 4; k++) {
            float h  = fminf(rintf(fmaxf(tc[k], 0.f) / s1), 255.f) * s1;
            float hq = fminf(fmaxf(rintf(h / s1b), -127.f), 127.f) * s1b;
            float xq = fminf(fmaxf(rintf(xc[k] / sx), -127.f), 127.f) * sx;
            o[k] = hq + xq;
            mm = fmaxf(mm, fabsf(o[k]));
        }
        float4 ov = {o[0], o[1], o[2], o[3]};
        r[i] = ov;
    }
    if (mOut) block_max_atomic(mm, mOut);
}

// ---------------- residual 2: emit NHWC bf16 code planes (j from dw2-path, i from r1) ----------------

__global__ __launch_bounds__(256) void residual2_codes_kernel(
    const float* __restrict__ t2, const float* __restrict__ r1,
    u16* __restrict__ jc, u16* __restrict__ ic, const unsigned* __restrict__ scal) {
    float s1  = fmaxf(ubits(scal[3]), EPSQ) / 255.f;
    float s1b = fmaxf(255.f * s1, EPSQ) / 127.f;
    float sx  = fmaxf(ubits(scal[2]), EPSQ) / 127.f;
    int b = blockIdx.x >> 8;
    long px0 = (long)(blockIdx.x & 255) * 64;
    __shared__ __align__(16) u16 lj[128 * 64];
    __shared__ __align__(16) u16 li[128 * 64];
    int px = threadIdx.x & 63, cq = threadIdx.x >> 6;
    for (int c0 = 0; c0 < 128; c0 += 4) {
        int c = c0 + cq;
        long g = ((long)b * Cc + c) * HW + px0 + px;
        float t = t2[g], x = r1[g];
        float hq = fminf(rintf(fmaxf(t, 0.f) / s1), 255.f) * s1;
        float j = fminf(fmaxf(rintf(hq / s1b), -127.f), 127.f);
        float i = fminf(fmaxf(rintf(x / sx), -127.f), 127.f);
        lj[c * 64 + px] = f2bf(j);
        li[c * 64 + px] = f2bf(i);
    }
    __syncthreads();
    int px2 = threadIdx.x & 63, csq = threadIdx.x >> 6;
    for (int it = 0; it < 4; it++) {
        int cs = it * 4 + csq;        // 0..15
        ushort8v pj, pi;
        #pragma unroll
        for (int k = 0; k < 8; k++) {
            pj[k] = lj[(cs * 8 + k) * 64 + px2];
            pi[k] = li[(cs * 8 + k) * 64 + px2];
        }
        long dst = ((long)b * HW + px0 + px2) * 128 + cs * 8;
        *reinterpret_cast<ushort8v*>(jc + dst) = pj;
        *reinterpret_cast<ushort8v*>(ic + dst) = pi;
    }
}

// ---------------- pointwise MFMA GEMM over bf16 integer codes ----------------
// Block: 256 thr = 4 waves, tile O=64 x px=64, wave quadrant 32x32.
// MODE 0: track relu max only. MODE 1: write quantized bf16 codes NHWC.
template<int K, bool DUAL, int MODE>
__global__ __launch_bounds__(256) void pwmfma_kernel(
    const u16* __restrict__ bc0, const u16* __restrict__ bc1,
    const u16* __restrict__ wc, const float* __restrict__ bias,
    u16* __restrict__ outc, const unsigned* __restrict__ scal,
    int O_total, int sInSlot, int sWSlot, int sOutSlot, unsigned* mslot) {

    __shared__ __align__(16) u16 lds[(DUAL ? 2 : 1) * 64 * K];
    int lane = threadIdx.x & 63, wv = threadIdx.x >> 6;
    int wm = wv >> 1, wn = wv & 1;
    int b = blockIdx.x >> 8;
    long px0 = (long)(blockIdx.x & 255) * 64;
    long pixbase = (long)b * HW + px0;
    int oB = blockIdx.y * 64;

    for (int s = threadIdx.x; s < 8 * K; s += 256) {        // 64 px * K/8 slots
        int px = s / (K / 8), cs = s % (K / 8);
        long gsrc = (pixbase + px) * K + cs * 8;
        int addr = (px * K * 2 + cs * 16) ^ ((px & 7) << 4);
        *reinterpret_cast<uint4v*>(reinterpret_cast<char*>(lds) + addr) =
            *reinterpret_cast<const uint4v*>(bc0 + gsrc);
        if (DUAL)
            *reinterpret_cast<uint4v*>(reinterpret_cast<char*>(lds) + 64 * K * 2 + addr) =
                *reinterpret_cast<const uint4v*>(bc1 + gsrc);
    }
    __syncthreads();

    const f32x4 z4 = {0.f, 0.f, 0.f, 0.f};
    f32x4 accA[2][2], accB[2][2];
    #pragma unroll
    for (int i = 0; i < 2; i++)
        #pragma unroll
        for (int j = 0; j < 2; j++) { accA[i][j] = z4; accB[i][j] = z4; }

    int kk = (lane >> 4) * 8;
    int n0 = wn * 32 + (lane & 15);
    long o0 = oB + wm * 32 + (lane & 15);
    #pragma unroll
    for (int kb = 0; kb < K / 32; kb++) {
        int kbase = kb * 32 + kk;
        short8v a0 = *reinterpret_cast<const short8v*>(wc + o0 * K + kbase);
        short8v a1 = *reinterpret_cast<const short8v*>(wc + (o0 + 16) * K + kbase);
        int ad0 = (n0 * K * 2 + kbase * 2) ^ ((n0 & 7) << 4);
        int ad1 = ((n0 + 16) * K * 2 + kbase * 2) ^ (((n0 + 16) & 7) << 4);
        short8v b0 = *reinterpret_cast<const short8v*>(reinterpret_cast<char*>(lds) + ad0);
        short8v b1 = *reinterpret_cast<const short8v*>(reinterpret_cast<char*>(lds) + ad1);
        accA[0][0] = MFMA16(a0, b0, accA[0][0]);
        accA[0][1] = MFMA16(a0, b1, accA[0][1]);
        accA[1][0] = MFMA16(a1, b0, accA[1][0]);
        accA[1][1] = MFMA16(a1, b1, accA[1][1]);
        if (DUAL) {
            short8v c0 = *reinterpret_cast<const short8v*>(reinterpret_cast<char*>(lds) + 64 * K * 2 + ad0);
            short8v c1 = *reinterpret_cast<const short8v*>(reinterpret_cast<char*>(lds) + 64 * K * 2 + ad1);
            accB[0][0] = MFMA16(a0, c0, accB[0][0]);
            accB[0][1] = MFMA16(a0, c1, accB[0][1]);
            accB[1][0] = MFMA16(a1, c0, accB[1][0]);
            accB[1][1] = MFMA16(a1, c1, accB[1][1]);
        }
    }

    float sW = ubits(scal[sWSlot]);
    float sA, sB_;
    if (DUAL) {
        float s1 = fmaxf(ubits(scal[3]), EPSQ) / 255.f;
        sA  = fmaxf(255.f * s1, EPSQ) / 127.f;     // == s1b used to make j codes
        sB_ = fmaxf(ubits(scal[2]), EPSQ) / 127.f; // == sx used to make i codes
    } else {
        sA = fmaxf(ubits(scal[sInSlot]), EPSQ) / 255.f;
        sB_ = 0.f;
    }

    if (MODE == 0) {
        float mm = 0.f;
        #pragma unroll
        for (int fm = 0; fm < 2; fm++)
        #pragma unroll
        for (int fn = 0; fn < 2; fn++)
        #pragma unroll
        for (int r = 0; r < 4; r++) {
            int o = oB + wm * 32 + fm * 16 + (lane >> 4) * 4 + r;
            float av = DUAL ? (sA * accA[fm][fn][r] + sB_ * accB[fm][fn][r])
                            : sA * accA[fm][fn][r];
            float v = fmaxf(sW * av + bias[o], 0.f);
            mm = fmaxf(mm, v);
        }
        block_max_atomic2(mm, mslot, reinterpret_cast<float*>(lds));
    } else {
        float sOut = fmaxf(ubits(scal[sOutSlot]), EPSQ) / 255.f;
        __syncthreads();                  // all waves done reading staged tile
        #pragma unroll
        for (int fm = 0; fm < 2; fm++)
        #pragma unroll
        for (int fn = 0; fn < 2; fn++) {
            ushort4v pk;
            #pragma unroll
            for (int r = 0; r < 4; r++) {
                int o = oB + wm * 32 + fm * 16 + (lane >> 4) * 4 + r;
                float av = DUAL ? (sA * accA[fm][fn][r] + sB_ * accB[fm][fn][r])
                                : sA * accA[fm][fn][r];
                float v = fmaxf(sW * av + bias[o], 0.f);
                pk[r] = f2bf(fminf(rintf(v / sOut), 255.f));
            }
            int pxl = wn * 32 + fn * 16 + (lane & 15);
            int orow = wm * 32 + fm * 16 + (lane >> 4) * 4;
            int ad = (pxl * 128 + orow * 2) ^ ((pxl & 7) << 4);
            *reinterpret_cast<ushort4v*>(reinterpret_cast<char*>(lds) + ad) = pk;
        }
        __syncthreads();
        for (int s = threadIdx.x; s < 512; s += 256) {
            int px = s >> 3, sl = s & 7;
            uint4v v = *reinterpret_cast<uint4v*>(
                reinterpret_cast<char*>(lds) + ((px * 128 + sl * 16) ^ ((px & 7) << 4)));
            *reinterpret_cast<uint4v*>(outc + (pixbase + px) * O_total + oB + sl * 8) = v;
        }
    }
}

// ---------------- 3x3 conv 128->256 MFMA over bf16 codes, fp32 NCHW out + max ----------------

__global__ __launch_bounds__(256) void conv3x3_mfma_kernel(
    const u16* __restrict__ xc,   // NHWC codes [B*HW][128]
    const u16* __restrict__ wc,   // [256][9][128] codes
    const float* __restrict__ bias, float* __restrict__ out,
    const unsigned* __restrict__ scal, unsigned* mslot) {

    __shared__ __align__(16) u16 lds[3 * 66 * 128];
    int lane = threadIdx.x & 63, wv = threadIdx.x >> 6;
    int wm = wv >> 1, wn = wv & 1;
    int bx = blockIdx.x;
    int b = bx >> 8, h = (bx >> 1) & 127, wseg = bx & 1;
    int oB = blockIdx.y * 64;

    // stage 3 rows x 66 cols x 128 ch (bf16), halo col may be OOB (zero-filled below)
    for (int s = threadIdx.x; s < 3 * 66 * 16; s += 256) {
        int row = s / (66 * 16), rem = s % (66 * 16), col = rem >> 4, sl = rem & 15;
        int hh = h + row - 1;
        if (hh < 0 || hh > 127) continue;      // row never read (tap skipped)
        int wgl = wseg * 64 + col - 1;         // -1..128 possible at edges
        long pix = (long)b * HW + (long)hh * 128 + wgl;
        uint4v v = *reinterpret_cast<const uint4v*>(xc + pix * 128 + sl * 8);
        int addr = ((row * 66 + col) * 256 + sl * 16) ^ ((col & 7) << 4);
        *reinterpret_cast<uint4v*>(reinterpret_cast<char*>(lds) + addr) = v;
    }
    __syncthreads();
    {   // zero the out-of-image halo column
        int col = wseg ? 65 : 0;
        if (threadIdx.x < 48) {
            int row = threadIdx.x >> 4, sl = threadIdx.x & 15;
            int addr = ((row * 66 + col) * 256 + sl * 16) ^ ((col & 7) << 4);
            uint4v z = {0, 0, 0, 0};
            *reinterpret_cast<uint4v*>(reinterpret_cast<char*>(lds) + addr) = z;
        }
    }
    __syncthreads();

    const f32x4 z4 = {0.f, 0.f, 0.f, 0.f};
    f32x4 acc[2][2];
    #pragma unroll
    for (int i = 0; i < 2; i++)
        #pragma unroll
        for (int j = 0; j < 2; j++) acc[i][j] = z4;

    int kk = (lane >> 4) * 8;
    int n0 = wn * 32 + (lane & 15);
    long o0 = oB + wm * 32 + (lane & 15);
    for (int di = 0; di < 3; di++) {
        int hh = h + di - 1;
        if (hh < 0 || hh > 127) continue;      // block-uniform
        for (int dj = 0; dj < 3; dj++) {
            int tap = di * 3 + dj;
            #pragma unroll
            for (int kb = 0; kb < 4; kb++) {
                int kbase = kb * 32 + kk;
                short8v a0 = *reinterpret_cast<const short8v*>(wc + (o0 * 9 + tap) * 128 + kbase);
                short8v a1 = *reinterpret_cast<const short8v*>(wc + ((o0 + 16) * 9 + tap) * 128 + kbase);
                int c0 = n0 + dj, c1 = c0 + 16;
                short8v b0 = *reinterpret_cast<const short8v*>(reinterpret_cast<char*>(lds) +
                    (((di * 66 + c0) * 256 + kbase * 2) ^ ((c0 & 7) << 4)));
                short8v b1 = *reinterpret_cast<const short8v*>(reinterpret_cast<char*>(lds) +
                    (((di * 66 + c1) * 256 + kbase * 2) ^ ((c1 & 7) << 4)));
                acc[0][0] = MFMA16(a0, b0, acc[0][0]);
                acc[0][1] = MFMA16(a0, b1, acc[0][1]);
                acc[1][0] = MFMA16(a1, b0, acc[1][0]);
                acc[1][1] = MFMA16(a1, b1, acc[1][1]);
            }
        }
    }

    float s5 = fmaxf(ubits(scal[5]), EPSQ) / 255.f;
    float sc = ubits(scal[10]) * s5;
    float mm = 0.f;
    #pragma unroll
    for (int fm = 0; fm < 2; fm++)
    #pragma unroll
    for (int fn = 0; fn < 2; fn++)
    #pragma unroll
    for (int r = 0; r < 4; r++) {
        int o  = oB + wm * 32 + fm * 16 + (lane >> 4) * 4 + r;
        int px = wseg * 64 + wn * 32 + fn * 16 + (lane & 15);
        float v = fmaxf(sc * acc[fm][fn][r] + bias[o], 0.f);
        mm = fmaxf(mm, v);
        out[((long)(b * CO + o)) * HW + h * 128 + px] = v;
    }
    block_max_atomic2(mm, mslot, reinterpret_cast<float*>(lds));
}

// ---------------- in-place quant of a relu'd tensor (255 levels) ----------------

__global__ void quant_inplace_kernel(float4* __restrict__ p, long n4,
                                     const unsigned* __restrict__ scal, int idx) {
    float s = fmaxf(__uint_as_float(scal[idx]), EPSQ) / 255.f;
    long i0 = (long)blockIdx.x * blockDim.x + threadIdx.x;
    long str = (long)gridDim.x * blockDim.x;
    for (long i = i0; i < n4; i += str) {
        float4 v = p[i];
        v.x = fminf(rintf(v.x / s), 255.f) * s;
        v.y = fminf(rintf(v.y / s), 255.f) * s;
        v.z = fminf(rintf(v.z / s), 255.f) * s;
        v.w = fminf(rintf(v.w / s), 255.f) * s;
        p[i] = v;
    }
}

// ---------------- launch ----------------

extern "C" void kernel_launch(void* const* d_in, const int* in_sizes, int n_in,
                              void* d_out, int out_size, void* d_ws, size_t ws_size,
                              hipStream_t stream) {
    (void)in_sizes; (void)n_in; (void)out_size; (void)ws_size;
    const float* x     = (const float*)d_in[0];
    const float* dw1_w = (const float*)d_in[1];
    const float* dw1_b = (const float*)d_in[2];
    const float* dw2_w = (const float*)d_in[3];
    const float* dw2_b = (const float*)d_in[4];
    const float* pw1_w = (const float*)d_in[5];
    const float* pw1_b = (const float*)d_in[6];
    const float* pw2_w = (const float*)d_in[7];
    const float* pw2_b = (const float*)d_in[8];
    const float* up_w  = (const float*)d_in[9];
    const float* up_b  = (const float*)d_in[10];
    float* out = (float*)d_out;
    float* ws  = (float*)d_ws;

    // ws layout (float units):
    // [0, NX)        Abuf fp32            (later: p1codes low half)
    // [NX, 2NX)      Bbuf fp32            (later: p1codes high half)
    // [2NX, 2NX+NX/2) jcode bf16 NX       (later: p2codes bf16 NX)
    // [2NX+NX/2, 3NX) icode bf16 NX
    // [3NX, ...)     weight area + scal
    float* Abuf = ws;
    float* Bbuf = ws + NX;
    u16*   jcode = (u16*)(ws + 2 * NX);
    u16*   icode = (u16*)(ws + 2 * NX + NX / 2);
    u16*   p1codes = (u16*)ws;              // NP1 bf16 over A+B (exact fit)
    u16*   p2codes = (u16*)(ws + 2 * NX);   // NX bf16 over jcode

    float* wbase   = ws + 3 * NX;
    float* wq_dw1 = wbase;          float* bq_dw1 = wbase + 1152;
    float* wq_dw2 = wbase + 1280;   float* bq_dw2 = wbase + 2432;
    float* bq_pw1 = wbase + 2560;
    float* bq_pw2 = wbase + 3072;
    float* bq_up  = wbase + 3200;
    u16*   wc_pw1 = (u16*)(wbase + 3456);    // 65536 codes -> 32768 floats
    u16*   wc_pw2 = (u16*)(wbase + 36224);   // 65536 codes
    u16*   wc_up  = (u16*)(wbase + 68992);   // 294912 codes -> 147456 floats
    unsigned* scal = (unsigned*)(wbase + 216448);
    // slots: 0 SX | 1 M1(dw1 relu) | 2 MR1(|r1|) | 3 M2(dw2 relu) | 4 M3(pw1 relu)
    //        5 M4(pw2 relu) | 6 M5(up relu) | 8 sW_pw1 | 9 sW_pw2 | 10 sW_up

    (void)hipMemsetAsync(scal, 0, 32 * sizeof(unsigned), stream);

    QW q0{dw1_w, wq_dw1, nullptr, 1152, 0, 0}, q1{dw1_b, bq_dw1, nullptr, 128, 0, 0},
       q2{dw2_w, wq_dw2, nullptr, 1152, 0, 0}, q3{dw2_b, bq_dw2, nullptr, 128, 0, 0},
       q4{pw1_w, nullptr, wc_pw1, 65536, 1, 8}, q5{pw1_b, bq_pw1, nullptr, 512, 0, 0},
       q6{pw2_w, nullptr, wc_pw2, 65536, 1, 9}, q7{pw2_b, bq_pw2, nullptr, 128, 0, 0},
       q8{up_w, nullptr, wc_up, 294912, 2, 10}, q9{up_b, bq_up, nullptr, 256, 0, 0};
    quant_weights_kernel<<<10, 256, 0, stream>>>(q0, q1, q2, q3, q4, q5, q6, q7, q8, q9, scal);

    absmax_kernel<<<2048, 256, 0, stream>>>(x, NX, scal + 0);

    // residual block 1 (fp32 path)
    dwconv_kernel<<<dim3(Bn * Cc, Hh / 8), 256, 0, stream>>>(x, wq_dw1, bq_dw1, Abuf, scal + 1);
    residual_kernel<<<4096, 256, 0, stream>>>((const float4*)Abuf, (const float4*)x,
                                              (float4*)Bbuf, scal, 1, 0, scal + 2);
    // residual block 2 -> bf16 NHWC code planes
    dwconv_kernel<<<dim3(Bn * Cc, Hh / 8), 256, 0, stream>>>(Bbuf, wq_dw2, bq_dw2, Abuf, scal + 3);
    residual2_codes_kernel<<<2048, 256, 0, stream>>>(Abuf, Bbuf, jcode, icode, scal);

    // pw1 (dual-plane exact GEMM): pass1 max -> slot4, pass2 codes -> p1codes
    pwmfma_kernel<128, true, 0><<<dim3(2048, 8), 256, 0, stream>>>(
        jcode, icode, wc_pw1, bq_pw1, nullptr, scal, C4, 0, 8, 0, scal + 4);
    pwmfma_kernel<128, true, 1><<<dim3(2048, 8), 256, 0, stream>>>(
        jcode, icode, wc_pw1, bq_pw1, p1codes, scal, C4, 0, 8, 4, nullptr);

    // pw2: pass1 max -> slot5, pass2 codes -> p2codes
    pwmfma_kernel<512, false, 0><<<dim3(2048, 2), 256, 0, stream>>>(
        p1codes, nullptr, wc_pw2, bq_pw2, nullptr, scal, Cc, 4, 9, 0, scal + 5);
    pwmfma_kernel<512, false, 1><<<dim3(2048, 2), 256, 0, stream>>>(
        p1codes, nullptr, wc_pw2, bq_pw2, p2codes, scal, Cc, 4, 9, 5, nullptr);

    // up 3x3 -> d_out fp32 + max slot6, then final quant in place
    conv3x3_mfma_kernel<<<dim3(2048, 4), 256, 0, stream>>>(p2codes, wc_up, bq_up, out, scal, scal + 6);
    quant_inplace_kernel<<<4096, 256, 0, stream>>>((float4*)out, NOUT / 4, scal, 6);
}

// Round 3
// 1121.237 us; speedup vs baseline: 4.8519x; 1.7752x over previous
//
#include <hip/hip_runtime.h>

#define EPSQ 1e-8f

typedef unsigned short u16;
typedef __attribute__((ext_vector_type(8))) short short8v;
typedef __attribute__((ext_vector_type(8))) unsigned short ushort8v;
typedef __attribute__((ext_vector_type(4))) unsigned short ushort4v;
typedef __attribute__((ext_vector_type(4))) float f32x4;
typedef __attribute__((ext_vector_type(4))) unsigned int uint4v;

static constexpr int  Bn = 8, Cc = 128, Hh = 128, Ww = 128, HW = Hh * Ww; // 16384
static constexpr int  C4 = 512, CO = 256;
static constexpr long NX   = (long)Bn * Cc * HW;   // 16,777,216
static constexpr long NOUT = (long)Bn * CO * HW;   // 33,554,432

#define MFMA16(a,b,c) __builtin_amdgcn_mfma_f32_16x16x32_bf16(a,b,c,0,0,0)

__device__ __forceinline__ u16 f2bf(float f) { return (u16)(__float_as_uint(f) >> 16); } // exact for small ints
__device__ __forceinline__ float ubits(unsigned u) { return __uint_as_float(u); }

// ---------------- reductions ----------------

__device__ __forceinline__ float block_reduce_max(float v) {
    __shared__ float sm[8];
    #pragma unroll
    for (int off = 32; off; off >>= 1) v = fmaxf(v, __shfl_down(v, off));
    int lane = threadIdx.x & 63, wid = threadIdx.x >> 6;
    int nw = (blockDim.x + 63) >> 6;
    if (lane == 0) sm[wid] = v;
    __syncthreads();
    float r = sm[0];
    for (int i = 1; i < nw; i++) r = fmaxf(r, sm[i]);
    __syncthreads();
    return r;
}

__device__ __forceinline__ void block_max_atomic(float v, unsigned* slot) {
    #pragma unroll
    for (int off = 32; off; off >>= 1) v = fmaxf(v, __shfl_down(v, off));
    __shared__ float sm[8];
    int lane = threadIdx.x & 63, wid = threadIdx.x >> 6;
    if (lane == 0) sm[wid] = v;
    __syncthreads();
    if (threadIdx.x == 0) {
        float m = sm[0];
        int nw = (blockDim.x + 63) >> 6;
        for (int i = 1; i < nw; i++) m = fmaxf(m, sm[i]);
        if (m > __uint_as_float(*(volatile unsigned*)slot))
            atomicMax(slot, __float_as_uint(m));
    }
    __syncthreads();
}

// version with caller-provided LDS scratch (for kernels whose static LDS is at the 64KB cap)
__device__ __forceinline__ void block_max_atomic2(float v, unsigned* slot, float* sm) {
    #pragma unroll
    for (int off = 32; off; off >>= 1) v = fmaxf(v, __shfl_down(v, off));
    int lane = threadIdx.x & 63, wid = threadIdx.x >> 6;
    __syncthreads();                       // LDS may be in use by other waves
    if (lane == 0) sm[wid] = v;
    __syncthreads();
    if (threadIdx.x == 0) {
        float m = sm[0];
        int nw = (blockDim.x + 63) >> 6;
        for (int i = 1; i < nw; i++) m = fmaxf(m, sm[i]);
        if (m > __uint_as_float(*(volatile unsigned*)slot))
            atomicMax(slot, __float_as_uint(m));
    }
}

// ---------------- absmax over big tensor ----------------

__global__ void absmax_kernel(const float* __restrict__ x, long n, unsigned* slot) {
    long i = (long)blockIdx.x * blockDim.x + threadIdx.x;
    long stride = (long)gridDim.x * blockDim.x;
    const float4* x4 = (const float4*)x;
    long n4 = n >> 2;
    float m = 0.f;
    for (long j = i; j < n4; j += stride) {
        float4 v = x4[j];
        m = fmaxf(m, fmaxf(fmaxf(fabsf(v.x), fabsf(v.y)), fmaxf(fabsf(v.z), fabsf(v.w))));
    }
    block_max_atomic(m, slot);
}

// ---------------- weight fake-quant (parallel: absmax pass + quantize pass) ----------------
// mode 0: write fp32 dequant to dstF. mode 1: write bf16 codes to dstC (same layout).
// mode 2: write bf16 codes transposed OIHW[o][c][t] -> [o][t][c] (3x3, C=128).
struct QW { const float* src; float* dstF; u16* dstC; int n; int mode; int slot; };

__device__ __forceinline__ QW qw_select(const QW& q0, const QW& q1, const QW& q2, const QW& q3,
                                        const QW& q4, const QW& q5, const QW& q6, const QW& q7,
                                        const QW& q8, const QW& q9, int t) {
    switch (t) {
        case 0: return q0; case 1: return q1; case 2: return q2; case 3: return q3;
        case 4: return q4; case 5: return q5; case 6: return q6; case 7: return q7;
        case 8: return q8; default: return q9;
    }
}

__global__ void wabsmax_kernel(QW q0, QW q1, QW q2, QW q3, QW q4,
                               QW q5, QW q6, QW q7, QW q8, QW q9,
                               unsigned* __restrict__ scal) {
    QW q = qw_select(q0, q1, q2, q3, q4, q5, q6, q7, q8, q9, blockIdx.y);
    int i0 = blockIdx.x * blockDim.x + threadIdx.x;
    int str = gridDim.x * blockDim.x;
    float m = 0.f;
    for (int i = i0; i < q.n; i += str) m = fmaxf(m, fabsf(q.src[i]));
    block_max_atomic(m, scal + 16 + blockIdx.y);
}

__global__ void wquant_kernel(QW q0, QW q1, QW q2, QW q3, QW q4,
                              QW q5, QW q6, QW q7, QW q8, QW q9,
                              unsigned* __restrict__ scal) {
    QW q = qw_select(q0, q1, q2, q3, q4, q5, q6, q7, q8, q9, blockIdx.y);
    float s = fmaxf(ubits(scal[16 + blockIdx.y]), EPSQ) / 127.f;
    if (q.mode != 0 && blockIdx.x == 0 && threadIdx.x == 0) scal[q.slot] = __float_as_uint(s);
    int i0 = blockIdx.x * blockDim.x + threadIdx.x;
    int str = gridDim.x * blockDim.x;
    for (int i = i0; i < q.n; i += str) {
        float v = fminf(fmaxf(rintf(q.src[i] / s), -127.f), 127.f);
        if (q.mode == 0) q.dstF[i] = v * s;
        else if (q.mode == 1) q.dstC[i] = f2bf(v);
        else {
            int o = i / 1152, rem = i % 1152, c = rem / 9, t = rem % 9;
            q.dstC[(o * 9 + t) * 128 + c] = f2bf(v);
        }
    }
}

// ---------------- depthwise 3x3 (pad 1), fp32 ----------------

__global__ void dwconv_kernel(const float* __restrict__ in, const float* __restrict__ wq,
                              const float* __restrict__ bq, float* __restrict__ out,
                              unsigned* mslot) {
    int bc = blockIdx.x;              // b*C + c
    int c  = bc & (Cc - 1);
    float w[9];
    #pragma unroll
    for (int k = 0; k < 9; k++) w[k] = wq[c * 9 + k];
    float bias = bq[c];
    const float* src = in + (long)bc * HW;
    float* dst = out + (long)bc * HW;
    int j  = threadIdx.x & (Ww - 1);
    int r2 = threadIdx.x >> 7;        // 0..1
    float mm = 0.f;
    #pragma unroll
    for (int rr = 0; rr < 4; rr++) {
        int i = blockIdx.y * 8 + rr * 2 + r2;
        float acc = 0.f;
        #pragma unroll
        for (int di = 0; di < 3; di++) {
            int ii = i + di - 1;
            if (ii < 0 || ii >= Hh) continue;
            #pragma unroll
            for (int dj = 0; dj < 3; dj++) {
                int jj = j + dj - 1;
                if (jj < 0 || jj >= Ww) continue;
                acc = fmaf(w[di * 3 + dj], src[ii * Ww + jj], acc);
            }
        }
        acc += bias;
        dst[i * Ww + j] = acc;
        mm = fmaxf(mm, fmaxf(acc, 0.f));
    }
    block_max_atomic(mm, mslot);
}

// ---------------- residual 1: r = fq(quant_relu(t)) + fq(x), fp32 out + max ----------------

__global__ void residual_kernel(const float4* __restrict__ t, const float4* __restrict__ xin,
                                float4* __restrict__ r, const unsigned* __restrict__ scal,
                                int mReluIdx, int mXIdx, unsigned* mOut) {
    float s1  = fmaxf(__uint_as_float(scal[mReluIdx]), EPSQ) / 255.f;
    float mh  = 255.f * s1;
    float s1b = fmaxf(mh, EPSQ) / 127.f;
    float sx  = fmaxf(__uint_as_float(scal[mXIdx]), EPSQ) / 127.f;
    long i0 = (long)blockIdx.x * blockDim.x + threadIdx.x;
    long str = (long)gridDim.x * blockDim.x;
    long n4 = NX >> 2;
    float mm = 0.f;
    for (long i = i0; i < n4; i += str) {
        float4 tv = t[i];
        float4 xv = xin[i];
        float o[4];
        float tc[4] = {tv.x, tv.y, tv.z, tv.w};
        float xc[4] = {xv.x, xv.y, xv.z, xv.w};
        #pragma unroll
        for (int k = 0; k < 4; k++) {
            float h  = fminf(rintf(fmaxf(tc[k], 0.f) / s1), 255.f) * s1;
            float hq = fminf(fmaxf(rintf(h / s1b), -127.f), 127.f) * s1b;
            float xq = fminf(fmaxf(rintf(xc[k] / sx), -127.f), 127.f) * sx;
            o[k] = hq + xq;
            mm = fmaxf(mm, fabsf(o[k]));
        }
        float4 ov = {o[0], o[1], o[2], o[3]};
        r[i] = ov;
    }
    if (mOut) block_max_atomic(mm, mOut);
}

// ---------------- residual 2: emit NHWC bf16 code planes (j from dw2-path, i from r1) ----------------

__global__ __launch_bounds__(256) void residual2_codes_kernel(
    const float* __restrict__ t2, const float* __restrict__ r1,
    u16* __restrict__ jc, u16* __restrict__ ic, const unsigned* __restrict__ scal) {
    float s1  = fmaxf(ubits(scal[3]), EPSQ) / 255.f;
    float s1b = fmaxf(255.f * s1, EPSQ) / 127.f;
    float sx  = fmaxf(ubits(scal[2]), EPSQ) / 127.f;
    int b = blockIdx.x >> 8;
    long px0 = (long)(blockIdx.x & 255) * 64;
    __shared__ __align__(16) u16 lj[128 * 64];
    __shared__ __align__(16) u16 li[128 * 64];
    int px = threadIdx.x & 63, cq = threadIdx.x >> 6;
    for (int c0 = 0; c0 < 128; c0 += 4) {
        int c = c0 + cq;
        long g = ((long)b * Cc + c) * HW + px0 + px;
        float t = t2[g], x = r1[g];
        float hq = fminf(rintf(fmaxf(t, 0.f) / s1), 255.f) * s1;
        float j = fminf(fmaxf(rintf(hq / s1b), -127.f), 127.f);
        float i = fminf(fmaxf(rintf(x / sx), -127.f), 127.f);
        lj[c * 64 + px] = f2bf(j);
        li[c * 64 + px] = f2bf(i);
    }
    __syncthreads();
    int px2 = threadIdx.x & 63, csq = threadIdx.x >> 6;
    for (int it = 0; it < 4; it++) {
        int cs = it * 4 + csq;        // 0..15
        ushort8v pj, pi;
        #pragma unroll
        for (int k = 0; k < 8; k++) {
            pj[k] = lj[(cs * 8 + k) * 64 + px2];
            pi[k] = li[(cs * 8 + k) * 64 + px2];
        }
        long dst = ((long)b * HW + px0 + px2) * 128 + cs * 8;
        *reinterpret_cast<ushort8v*>(jc + dst) = pj;
        *reinterpret_cast<ushort8v*>(ic + dst) = pi;
    }
}

// ---------------- pointwise MFMA GEMM over bf16 integer codes ----------------
// Block: 256 thr = 4 waves, tile O=64 x px=64, wave quadrant 32x32.
// MODE 0: track relu max only. MODE 1: write quantized bf16 codes NHWC.
template<int K, bool DUAL, int MODE>
__global__ __launch_bounds__(256) void pwmfma_kernel(
    const u16* __restrict__ bc0, const u16* __restrict__ bc1,
    const u16* __restrict__ wc, const float* __restrict__ bias,
    u16* __restrict__ outc, const unsigned* __restrict__ scal,
    int O_total, int sInSlot, int sWSlot, int sOutSlot, unsigned* mslot) {

    __shared__ __align__(16) u16 lds[(DUAL ? 2 : 1) * 64 * K];
    int lane = threadIdx.x & 63, wv = threadIdx.x >> 6;
    int wm = wv >> 1, wn = wv & 1;
    int b = blockIdx.x >> 8;
    long px0 = (long)(blockIdx.x & 255) * 64;
    long pixbase = (long)b * HW + px0;
    int oB = blockIdx.y * 64;

    for (int s = threadIdx.x; s < 8 * K; s += 256) {        // 64 px * K/8 slots
        int px = s / (K / 8), cs = s % (K / 8);
        long gsrc = (pixbase + px) * K + cs * 8;
        int addr = (px * K * 2 + cs * 16) ^ ((px & 7) << 4);
        *reinterpret_cast<uint4v*>(reinterpret_cast<char*>(lds) + addr) =
            *reinterpret_cast<const uint4v*>(bc0 + gsrc);
        if (DUAL)
            *reinterpret_cast<uint4v*>(reinterpret_cast<char*>(lds) + 64 * K * 2 + addr) =
                *reinterpret_cast<const uint4v*>(bc1 + gsrc);
    }
    __syncthreads();

    const f32x4 z4 = {0.f, 0.f, 0.f, 0.f};
    f32x4 accA[2][2], accB[2][2];
    #pragma unroll
    for (int i = 0; i < 2; i++)
        #pragma unroll
        for (int j = 0; j < 2; j++) { accA[i][j] = z4; accB[i][j] = z4; }

    int kk = (lane >> 4) * 8;
    int n0 = wn * 32 + (lane & 15);
    long o0 = oB + wm * 32 + (lane & 15);
    #pragma unroll
    for (int kb = 0; kb < K / 32; kb++) {
        int kbase = kb * 32 + kk;
        short8v a0 = *reinterpret_cast<const short8v*>(wc + o0 * K + kbase);
        short8v a1 = *reinterpret_cast<const short8v*>(wc + (o0 + 16) * K + kbase);
        int ad0 = (n0 * K * 2 + kbase * 2) ^ ((n0 & 7) << 4);
        int ad1 = ((n0 + 16) * K * 2 + kbase * 2) ^ (((n0 + 16) & 7) << 4);
        short8v b0 = *reinterpret_cast<const short8v*>(reinterpret_cast<char*>(lds) + ad0);
        short8v b1 = *reinterpret_cast<const short8v*>(reinterpret_cast<char*>(lds) + ad1);
        accA[0][0] = MFMA16(a0, b0, accA[0][0]);
        accA[0][1] = MFMA16(a0, b1, accA[0][1]);
        accA[1][0] = MFMA16(a1, b0, accA[1][0]);
        accA[1][1] = MFMA16(a1, b1, accA[1][1]);
        if (DUAL) {
            short8v c0 = *reinterpret_cast<const short8v*>(reinterpret_cast<char*>(lds) + 64 * K * 2 + ad0);
            short8v c1 = *reinterpret_cast<const short8v*>(reinterpret_cast<char*>(lds) + 64 * K * 2 + ad1);
            accB[0][0] = MFMA16(a0, c0, accB[0][0]);
            accB[0][1] = MFMA16(a0, c1, accB[0][1]);
            accB[1][0] = MFMA16(a1, c0, accB[1][0]);
            accB[1][1] = MFMA16(a1, c1, accB[1][1]);
        }
    }

    float sW = ubits(scal[sWSlot]);
    float sA, sB_;
    if (DUAL) {
        float s1 = fmaxf(ubits(scal[3]), EPSQ) / 255.f;
        sA  = fmaxf(255.f * s1, EPSQ) / 127.f;     // == s1b used to make j codes
        sB_ = fmaxf(ubits(scal[2]), EPSQ) / 127.f; // == sx used to make i codes
    } else {
        sA = fmaxf(ubits(scal[sInSlot]), EPSQ) / 255.f;
        sB_ = 0.f;
    }

    if (MODE == 0) {
        float mm = 0.f;
        #pragma unroll
        for (int fm = 0; fm < 2; fm++)
        #pragma unroll
        for (int fn = 0; fn < 2; fn++)
        #pragma unroll
        for (int r = 0; r < 4; r++) {
            int o = oB + wm * 32 + fm * 16 + (lane >> 4) * 4 + r;
            float av = DUAL ? (sA * accA[fm][fn][r] + sB_ * accB[fm][fn][r])
                            : sA * accA[fm][fn][r];
            float v = fmaxf(sW * av + bias[o], 0.f);
            mm = fmaxf(mm, v);
        }
        block_max_atomic2(mm, mslot, reinterpret_cast<float*>(lds));
    } else {
        float sOut = fmaxf(ubits(scal[sOutSlot]), EPSQ) / 255.f;
        __syncthreads();                  // all waves done reading staged tile
        #pragma unroll
        for (int fm = 0; fm < 2; fm++)
        #pragma unroll
        for (int fn = 0; fn < 2; fn++) {
            ushort4v pk;
            #pragma unroll
            for (int r = 0; r < 4; r++) {
                int o = oB + wm * 32 + fm * 16 + (lane >> 4) * 4 + r;
                float av = DUAL ? (sA * accA[fm][fn][r] + sB_ * accB[fm][fn][r])
                                : sA * accA[fm][fn][r];
                float v = fmaxf(sW * av + bias[o], 0.f);
                pk[r] = f2bf(fminf(rintf(v / sOut), 255.f));
            }
            int pxl = wn * 32 + fn * 16 + (lane & 15);
            int orow = wm * 32 + fm * 16 + (lane >> 4) * 4;
            int ad = (pxl * 128 + orow * 2) ^ ((pxl & 7) << 4);
            *reinterpret_cast<ushort4v*>(reinterpret_cast<char*>(lds) + ad) = pk;
        }
        __syncthreads();
        for (int s = threadIdx.x; s < 512; s += 256) {
            int px = s >> 3, sl = s & 7;
            uint4v v = *reinterpret_cast<uint4v*>(
                reinterpret_cast<char*>(lds) + ((px * 128 + sl * 16) ^ ((px & 7) << 4)));
            *reinterpret_cast<uint4v*>(outc + (pixbase + px) * O_total + oB + sl * 8) = v;
        }
    }
}

// ---------------- 3x3 conv 128->256 MFMA over bf16 codes, fp32 NCHW out + max ----------------

__global__ __launch_bounds__(256) void conv3x3_mfma_kernel(
    const u16* __restrict__ xc,   // NHWC codes [B*HW][128]
    const u16* __restrict__ wc,   // [256][9][128] codes
    const float* __restrict__ bias, float* __restrict__ out,
    const unsigned* __restrict__ scal, unsigned* mslot) {

    __shared__ __align__(16) u16 lds[3 * 66 * 128];
    int lane = threadIdx.x & 63, wv = threadIdx.x >> 6;
    int wm = wv >> 1, wn = wv & 1;
    int bx = blockIdx.x;
    int b = bx >> 8, h = (bx >> 1) & 127, wseg = bx & 1;
    int oB = blockIdx.y * 64;

    // stage 3 rows x 66 cols x 128 ch (bf16), halo col may be OOB (zero-filled below)
    for (int s = threadIdx.x; s < 3 * 66 * 16; s += 256) {
        int row = s / (66 * 16), rem = s % (66 * 16), col = rem >> 4, sl = rem & 15;
        int hh = h + row - 1;
        if (hh < 0 || hh > 127) continue;      // row never read (tap skipped)
        int wgl = wseg * 64 + col - 1;         // -1..128 possible at edges
        long pix = (long)b * HW + (long)hh * 128 + wgl;
        uint4v v = *reinterpret_cast<const uint4v*>(xc + pix * 128 + sl * 8);
        int addr = ((row * 66 + col) * 256 + sl * 16) ^ ((col & 7) << 4);
        *reinterpret_cast<uint4v*>(reinterpret_cast<char*>(lds) + addr) = v;
    }
    __syncthreads();
    {   // zero the out-of-image halo column
        int col = wseg ? 65 : 0;
        if (threadIdx.x < 48) {
            int row = threadIdx.x >> 4, sl = threadIdx.x & 15;
            int addr = ((row * 66 + col) * 256 + sl * 16) ^ ((col & 7) << 4);
            uint4v z = {0, 0, 0, 0};
            *reinterpret_cast<uint4v*>(reinterpret_cast<char*>(lds) + addr) = z;
        }
    }
    __syncthreads();

    const f32x4 z4 = {0.f, 0.f, 0.f, 0.f};
    f32x4 acc[2][2];
    #pragma unroll
    for (int i = 0; i < 2; i++)
        #pragma unroll
        for (int j = 0; j < 2; j++) acc[i][j] = z4;

    int kk = (lane >> 4) * 8;
    int n0 = wn * 32 + (lane & 15);
    long o0 = oB + wm * 32 + (lane & 15);
    for (int di = 0; di < 3; di++) {
        int hh = h + di - 1;
        if (hh < 0 || hh > 127) continue;      // block-uniform
        for (int dj = 0; dj < 3; dj++) {
            int tap = di * 3 + dj;
            #pragma unroll
            for (int kb = 0; kb < 4; kb++) {
                int kbase = kb * 32 + kk;
                short8v a0 = *reinterpret_cast<const short8v*>(wc + (o0 * 9 + tap) * 128 + kbase);
                short8v a1 = *reinterpret_cast<const short8v*>(wc + ((o0 + 16) * 9 + tap) * 128 + kbase);
                int c0 = n0 + dj, c1 = c0 + 16;
                short8v b0 = *reinterpret_cast<const short8v*>(reinterpret_cast<char*>(lds) +
                    (((di * 66 + c0) * 256 + kbase * 2) ^ ((c0 & 7) << 4)));
                short8v b1 = *reinterpret_cast<const short8v*>(reinterpret_cast<char*>(lds) +
                    (((di * 66 + c1) * 256 + kbase * 2) ^ ((c1 & 7) << 4)));
                acc[0][0] = MFMA16(a0, b0, acc[0][0]);
                acc[0][1] = MFMA16(a0, b1, acc[0][1]);
                acc[1][0] = MFMA16(a1, b0, acc[1][0]);
                acc[1][1] = MFMA16(a1, b1, acc[1][1]);
            }
        }
    }

    float s5 = fmaxf(ubits(scal[5]), EPSQ) / 255.f;
    float sc = ubits(scal[10]) * s5;
    float mm = 0.f;
    #pragma unroll
    for (int fm = 0; fm < 2; fm++)
    #pragma unroll
    for (int fn = 0; fn < 2; fn++)
    #pragma unroll
    for (int r = 0; r < 4; r++) {
        int o  = oB + wm * 32 + fm * 16 + (lane >> 4) * 4 + r;
        int px = wseg * 64 + wn * 32 + fn * 16 + (lane & 15);
        float v = fmaxf(sc * acc[fm][fn][r] + bias[o], 0.f);
        mm = fmaxf(mm, v);
        out[((long)(b * CO + o)) * HW + h * 128 + px] = v;
    }
    block_max_atomic2(mm, mslot, reinterpret_cast<float*>(lds));
}

// ---------------- in-place quant of a relu'd tensor (255 levels) ----------------

__global__ void quant_inplace_kernel(float4* __restrict__ p, long n4,
                                     const unsigned* __restrict__ scal, int idx) {
    float s = fmaxf(__uint_as_float(scal[idx]), EPSQ) / 255.f;
    long i0 = (long)blockIdx.x * blockDim.x + threadIdx.x;
    long str = (long)gridDim.x * blockDim.x;
    for (long i = i0; i < n4; i += str) {
        float4 v = p[i];
        v.x = fminf(rintf(v.x / s), 255.f) * s;
        v.y = fminf(rintf(v.y / s), 255.f) * s;
        v.z = fminf(rintf(v.z / s), 255.f) * s;
        v.w = fminf(rintf(v.w / s), 255.f) * s;
        p[i] = v;
    }
}

// ---------------- launch ----------------

extern "C" void kernel_launch(void* const* d_in, const int* in_sizes, int n_in,
                              void* d_out, int out_size, void* d_ws, size_t ws_size,
                              hipStream_t stream) {
    (void)in_sizes; (void)n_in; (void)out_size; (void)ws_size;
    const float* x     = (const float*)d_in[0];
    const float* dw1_w = (const float*)d_in[1];
    const float* dw1_b = (const float*)d_in[2];
    const float* dw2_w = (const float*)d_in[3];
    const float* dw2_b = (const float*)d_in[4];
    const float* pw1_w = (const float*)d_in[5];
    const float* pw1_b = (const float*)d_in[6];
    const float* pw2_w = (const float*)d_in[7];
    const float* pw2_b = (const float*)d_in[8];
    const float* up_w  = (const float*)d_in[9];
    const float* up_b  = (const float*)d_in[10];
    float* out = (float*)d_out;
    float* ws  = (float*)d_ws;

    // ws layout (float units):
    // [0, NX)        Abuf fp32            (later: p1codes low half)
    // [NX, 2NX)      Bbuf fp32            (later: p1codes high half)
    // [2NX, 2NX+NX/2) jcode bf16 NX       (later: p2codes bf16 NX)
    // [2NX+NX/2, 3NX) icode bf16 NX
    // [3NX, ...)     weight area + scal
    float* Abuf = ws;
    float* Bbuf = ws + NX;
    u16*   jcode = (u16*)(ws + 2 * NX);
    u16*   icode = (u16*)(ws + 2 * NX + NX / 2);
    u16*   p1codes = (u16*)ws;              // NP1 bf16 over A+B (exact fit)
    u16*   p2codes = (u16*)(ws + 2 * NX);   // NX bf16 over jcode

    float* wbase   = ws + 3 * NX;
    float* wq_dw1 = wbase;          float* bq_dw1 = wbase + 1152;
    float* wq_dw2 = wbase + 1280;   float* bq_dw2 = wbase + 2432;
    float* bq_pw1 = wbase + 2560;
    float* bq_pw2 = wbase + 3072;
    float* bq_up  = wbase + 3200;
    u16*   wc_pw1 = (u16*)(wbase + 3456);    // 65536 codes -> 32768 floats
    u16*   wc_pw2 = (u16*)(wbase + 36224);   // 65536 codes
    u16*   wc_up  = (u16*)(wbase + 68992);   // 294912 codes -> 147456 floats
    unsigned* scal = (unsigned*)(wbase + 216448);
    // slots: 0 SX | 1 M1(dw1 relu) | 2 MR1(|r1|) | 3 M2(dw2 relu) | 4 M3(pw1 relu)
    //        5 M4(pw2 relu) | 6 M5(up relu) | 8 sW_pw1 | 9 sW_pw2 | 10 sW_up
    //        16..25 raw weight-tensor absmax

    (void)hipMemsetAsync(scal, 0, 32 * sizeof(unsigned), stream);

    QW q0{dw1_w, wq_dw1, nullptr, 1152, 0, 0}, q1{dw1_b, bq_dw1, nullptr, 128, 0, 0},
       q2{dw2_w, wq_dw2, nullptr, 1152, 0, 0}, q3{dw2_b, bq_dw2, nullptr, 128, 0, 0},
       q4{pw1_w, nullptr, wc_pw1, 65536, 1, 8}, q5{pw1_b, bq_pw1, nullptr, 512, 0, 0},
       q6{pw2_w, nullptr, wc_pw2, 65536, 1, 9}, q7{pw2_b, bq_pw2, nullptr, 128, 0, 0},
       q8{up_w, nullptr, wc_up, 294912, 2, 10}, q9{up_b, bq_up, nullptr, 256, 0, 0};
    wabsmax_kernel<<<dim3(32, 10), 256, 0, stream>>>(q0, q1, q2, q3, q4, q5, q6, q7, q8, q9, scal);
    wquant_kernel<<<dim3(32, 10), 256, 0, stream>>>(q0, q1, q2, q3, q4, q5, q6, q7, q8, q9, scal);

    absmax_kernel<<<2048, 256, 0, stream>>>(x, NX, scal + 0);

    // residual block 1 (fp32 path)
    dwconv_kernel<<<dim3(Bn * Cc, Hh / 8), 256, 0, stream>>>(x, wq_dw1, bq_dw1, Abuf, scal + 1);
    residual_kernel<<<4096, 256, 0, stream>>>((const float4*)Abuf, (const float4*)x,
                                              (float4*)Bbuf, scal, 1, 0, scal + 2);
    // residual block 2 -> bf16 NHWC code planes
    dwconv_kernel<<<dim3(Bn * Cc, Hh / 8), 256, 0, stream>>>(Bbuf, wq_dw2, bq_dw2, Abuf, scal + 3);
    residual2_codes_kernel<<<2048, 256, 0, stream>>>(Abuf, Bbuf, jcode, icode, scal);

    // pw1 (dual-plane exact GEMM): pass1 max -> slot4, pass2 codes -> p1codes
    pwmfma_kernel<128, true, 0><<<dim3(2048, 8), 256, 0, stream>>>(
        jcode, icode, wc_pw1, bq_pw1, nullptr, scal, C4, 0, 8, 0, scal + 4);
    pwmfma_kernel<128, true, 1><<<dim3(2048, 8), 256, 0, stream>>>(
        jcode, icode, wc_pw1, bq_pw1, p1codes, scal, C4, 0, 8, 4, nullptr);

    // pw2: pass1 max -> slot5, pass2 codes -> p2codes
    pwmfma_kernel<512, false, 0><<<dim3(2048, 2), 256, 0, stream>>>(
        p1codes, nullptr, wc_pw2, bq_pw2, nullptr, scal, Cc, 4, 9, 0, scal + 5);
    pwmfma_kernel<512, false, 1><<<dim3(2048, 2), 256, 0, stream>>>(
        p1codes, nullptr, wc_pw2, bq_pw2, p2codes, scal, Cc, 4, 9, 5, nullptr);

    // up 3x3 -> d_out fp32 + max slot6, then final quant in place
    conv3x3_mfma_kernel<<<dim3(2048, 4), 256, 0, stream>>>(p2codes, wc_up, bq_up, out, scal, scal + 6);
    quant_inplace_kernel<<<4096, 256, 0, stream>>>((float4*)out, NOUT / 4, scal, 6);
}

// Round 4
// 828.589 us; speedup vs baseline: 6.5655x; 1.3532x over previous
//
#include <hip/hip_runtime.h>

#define EPSQ 1e-8f

typedef unsigned short u16;
typedef __attribute__((ext_vector_type(8))) short short8v;
typedef __attribute__((ext_vector_type(8))) unsigned short ushort8v;
typedef __attribute__((ext_vector_type(4))) unsigned short ushort4v;
typedef __attribute__((ext_vector_type(4))) float f32x4;
typedef __attribute__((ext_vector_type(4))) unsigned int uint4v;

static constexpr int  Bn = 8, Cc = 128, Hh = 128, Ww = 128, HW = Hh * Ww; // 16384
static constexpr int  C4 = 512, CO = 256;
static constexpr long NX   = (long)Bn * Cc * HW;   // 16,777,216
static constexpr long NOUT = (long)Bn * CO * HW;   // 33,554,432

#define MFMA16(a,b,c) __builtin_amdgcn_mfma_f32_16x16x32_bf16(a,b,c,0,0,0)

__device__ __forceinline__ u16 f2bf(float f) { return (u16)(__float_as_uint(f) >> 16); } // exact for small ints
__device__ __forceinline__ float ubits(unsigned u) { return __uint_as_float(u); }

// ---------------- reductions ----------------

__device__ __forceinline__ float block_reduce_max(float v) {
    __shared__ float sm[8];
    #pragma unroll
    for (int off = 32; off; off >>= 1) v = fmaxf(v, __shfl_down(v, off));
    int lane = threadIdx.x & 63, wid = threadIdx.x >> 6;
    int nw = (blockDim.x + 63) >> 6;
    if (lane == 0) sm[wid] = v;
    __syncthreads();
    float r = sm[0];
    for (int i = 1; i < nw; i++) r = fmaxf(r, sm[i]);
    __syncthreads();
    return r;
}

__device__ __forceinline__ void block_max_atomic(float v, unsigned* slot) {
    #pragma unroll
    for (int off = 32; off; off >>= 1) v = fmaxf(v, __shfl_down(v, off));
    __shared__ float sm[8];
    int lane = threadIdx.x & 63, wid = threadIdx.x >> 6;
    if (lane == 0) sm[wid] = v;
    __syncthreads();
    if (threadIdx.x == 0) {
        float m = sm[0];
        int nw = (blockDim.x + 63) >> 6;
        for (int i = 1; i < nw; i++) m = fmaxf(m, sm[i]);
        if (m > __uint_as_float(*(volatile unsigned*)slot))
            atomicMax(slot, __float_as_uint(m));
    }
    __syncthreads();
}

// version with caller-provided LDS scratch (for kernels whose static LDS is large)
__device__ __forceinline__ void block_max_atomic2(float v, unsigned* slot, float* sm) {
    #pragma unroll
    for (int off = 32; off; off >>= 1) v = fmaxf(v, __shfl_down(v, off));
    int lane = threadIdx.x & 63, wid = threadIdx.x >> 6;
    __syncthreads();                       // LDS may be in use by other waves
    if (lane == 0) sm[wid] = v;
    __syncthreads();
    if (threadIdx.x == 0) {
        float m = sm[0];
        int nw = (blockDim.x + 63) >> 6;
        for (int i = 1; i < nw; i++) m = fmaxf(m, sm[i]);
        if (m > __uint_as_float(*(volatile unsigned*)slot))
            atomicMax(slot, __float_as_uint(m));
    }
}

// ---------------- absmax over big tensor ----------------

__global__ void absmax_kernel(const float* __restrict__ x, long n, unsigned* slot) {
    long i = (long)blockIdx.x * blockDim.x + threadIdx.x;
    long stride = (long)gridDim.x * blockDim.x;
    const float4* x4 = (const float4*)x;
    long n4 = n >> 2;
    float m = 0.f;
    for (long j = i; j < n4; j += stride) {
        float4 v = x4[j];
        m = fmaxf(m, fmaxf(fmaxf(fabsf(v.x), fabsf(v.y)), fmaxf(fabsf(v.z), fabsf(v.w))));
    }
    block_max_atomic(m, slot);
}

// ---------------- weight fake-quant (parallel: absmax pass + quantize pass) ----------------
// mode 0: write fp32 dequant to dstF. mode 1: write bf16 codes to dstC (same layout).
// mode 2: write bf16 codes transposed OIHW[o][c][t] -> [o][t][c] (3x3, C=128).
struct QW { const float* src; float* dstF; u16* dstC; int n; int mode; int slot; };

__device__ __forceinline__ QW qw_select(const QW& q0, const QW& q1, const QW& q2, const QW& q3,
                                        const QW& q4, const QW& q5, const QW& q6, const QW& q7,
                                        const QW& q8, const QW& q9, int t) {
    switch (t) {
        case 0: return q0; case 1: return q1; case 2: return q2; case 3: return q3;
        case 4: return q4; case 5: return q5; case 6: return q6; case 7: return q7;
        case 8: return q8; default: return q9;
    }
}

__global__ void wabsmax_kernel(QW q0, QW q1, QW q2, QW q3, QW q4,
                               QW q5, QW q6, QW q7, QW q8, QW q9,
                               unsigned* __restrict__ scal) {
    QW q = qw_select(q0, q1, q2, q3, q4, q5, q6, q7, q8, q9, blockIdx.y);
    int i0 = blockIdx.x * blockDim.x + threadIdx.x;
    int str = gridDim.x * blockDim.x;
    float m = 0.f;
    for (int i = i0; i < q.n; i += str) m = fmaxf(m, fabsf(q.src[i]));
    block_max_atomic(m, scal + 16 + blockIdx.y);
}

__global__ void wquant_kernel(QW q0, QW q1, QW q2, QW q3, QW q4,
                              QW q5, QW q6, QW q7, QW q8, QW q9,
                              unsigned* __restrict__ scal) {
    QW q = qw_select(q0, q1, q2, q3, q4, q5, q6, q7, q8, q9, blockIdx.y);
    float s = fmaxf(ubits(scal[16 + blockIdx.y]), EPSQ) / 127.f;
    if (q.mode != 0 && blockIdx.x == 0 && threadIdx.x == 0) scal[q.slot] = __float_as_uint(s);
    int i0 = blockIdx.x * blockDim.x + threadIdx.x;
    int str = gridDim.x * blockDim.x;
    for (int i = i0; i < q.n; i += str) {
        float v = fminf(fmaxf(rintf(q.src[i] / s), -127.f), 127.f);
        if (q.mode == 0) q.dstF[i] = v * s;
        else if (q.mode == 1) q.dstC[i] = f2bf(v);
        else {
            int o = i / 1152, rem = i % 1152, c = rem / 9, t = rem % 9;
            q.dstC[(o * 9 + t) * 128 + c] = f2bf(v);
        }
    }
}

// ---------------- depthwise 3x3 (pad 1), fp32 ----------------

__global__ void dwconv_kernel(const float* __restrict__ in, const float* __restrict__ wq,
                              const float* __restrict__ bq, float* __restrict__ out,
                              unsigned* mslot) {
    int bc = blockIdx.x;              // b*C + c
    int c  = bc & (Cc - 1);
    float w[9];
    #pragma unroll
    for (int k = 0; k < 9; k++) w[k] = wq[c * 9 + k];
    float bias = bq[c];
    const float* src = in + (long)bc * HW;
    float* dst = out + (long)bc * HW;
    int j  = threadIdx.x & (Ww - 1);
    int r2 = threadIdx.x >> 7;        // 0..1
    float mm = 0.f;
    #pragma unroll
    for (int rr = 0; rr < 4; rr++) {
        int i = blockIdx.y * 8 + rr * 2 + r2;
        float acc = 0.f;
        #pragma unroll
        for (int di = 0; di < 3; di++) {
            int ii = i + di - 1;
            if (ii < 0 || ii >= Hh) continue;
            #pragma unroll
            for (int dj = 0; dj < 3; dj++) {
                int jj = j + dj - 1;
                if (jj < 0 || jj >= Ww) continue;
                acc = fmaf(w[di * 3 + dj], src[ii * Ww + jj], acc);
            }
        }
        acc += bias;
        dst[i * Ww + j] = acc;
        mm = fmaxf(mm, fmaxf(acc, 0.f));
    }
    block_max_atomic(mm, mslot);
}

// ---------------- residual 1: r = fq(quant_relu(t)) + fq(x), fp32 out + max ----------------

__global__ void residual_kernel(const float4* __restrict__ t, const float4* __restrict__ xin,
                                float4* __restrict__ r, const unsigned* __restrict__ scal,
                                int mReluIdx, int mXIdx, unsigned* mOut) {
    float s1  = fmaxf(__uint_as_float(scal[mReluIdx]), EPSQ) / 255.f;
    float mh  = 255.f * s1;
    float s1b = fmaxf(mh, EPSQ) / 127.f;
    float sx  = fmaxf(__uint_as_float(scal[mXIdx]), EPSQ) / 127.f;
    long i0 = (long)blockIdx.x * blockDim.x + threadIdx.x;
    long str = (long)gridDim.x * blockDim.x;
    long n4 = NX >> 2;
    float mm = 0.f;
    for (long i = i0; i < n4; i += str) {
        float4 tv = t[i];
        float4 xv = xin[i];
        float o[4];
        float tc[4] = {tv.x, tv.y, tv.z, tv.w};
        float xc[4] = {xv.x, xv.y, xv.z, xv.w};
        #pragma unroll
        for (int k = 0; k < 4; k++) {
            float h  = fminf(rintf(fmaxf(tc[k], 0.f) / s1), 255.f) * s1;
            float hq = fminf(fmaxf(rintf(h / s1b), -127.f), 127.f) * s1b;
            float xq = fminf(fmaxf(rintf(xc[k] / sx), -127.f), 127.f) * sx;
            o[k] = hq + xq;
            mm = fmaxf(mm, fabsf(o[k]));
        }
        float4 ov = {o[0], o[1], o[2], o[3]};
        r[i] = ov;
    }
    if (mOut) block_max_atomic(mm, mOut);
}

// ---------------- residual 2: emit NHWC bf16 code planes (j from dw2-path, i from r1) ----------------

__global__ __launch_bounds__(256) void residual2_codes_kernel(
    const float* __restrict__ t2, const float* __restrict__ r1,
    u16* __restrict__ jc, u16* __restrict__ ic, const unsigned* __restrict__ scal) {
    float s1  = fmaxf(ubits(scal[3]), EPSQ) / 255.f;
    float s1b = fmaxf(255.f * s1, EPSQ) / 127.f;
    float sx  = fmaxf(ubits(scal[2]), EPSQ) / 127.f;
    int b = blockIdx.x >> 8;
    long px0 = (long)(blockIdx.x & 255) * 64;
    __shared__ __align__(16) u16 lj[128 * 64];
    __shared__ __align__(16) u16 li[128 * 64];
    int px = threadIdx.x & 63, cq = threadIdx.x >> 6;
    for (int c0 = 0; c0 < 128; c0 += 4) {
        int c = c0 + cq;
        long g = ((long)b * Cc + c) * HW + px0 + px;
        float t = t2[g], x = r1[g];
        float hq = fminf(rintf(fmaxf(t, 0.f) / s1), 255.f) * s1;
        float j = fminf(fmaxf(rintf(hq / s1b), -127.f), 127.f);
        float i = fminf(fmaxf(rintf(x / sx), -127.f), 127.f);
        lj[c * 64 + px] = f2bf(j);
        li[c * 64 + px] = f2bf(i);
    }
    __syncthreads();
    int px2 = threadIdx.x & 63, csq = threadIdx.x >> 6;
    for (int it = 0; it < 4; it++) {
        int cs = it * 4 + csq;        // 0..15
        ushort8v pj, pi;
        #pragma unroll
        for (int k = 0; k < 8; k++) {
            pj[k] = lj[(cs * 8 + k) * 64 + px2];
            pi[k] = li[(cs * 8 + k) * 64 + px2];
        }
        long dst = ((long)b * HW + px0 + px2) * 128 + cs * 8;
        *reinterpret_cast<ushort8v*>(jc + dst) = pj;
        *reinterpret_cast<ushort8v*>(ic + dst) = pi;
    }
}

// ---------------- pointwise MFMA GEMM over bf16 integer codes ----------------
// Block: 256 thr = 4 waves. Tile: OB outputs x 64 px. Wave wv owns o-range wv*(OB/4).
// Activation tile staged ONCE per block (o fully merged -> minimal refetch).
// MODE 0: track relu max only. MODE 1: write quantized bf16 codes NHWC.
template<int K, int OB, bool DUAL, int MODE>
__global__ __launch_bounds__(256) void pwmfma_kernel(
    const u16* __restrict__ bc0, const u16* __restrict__ bc1,
    const u16* __restrict__ wc, const float* __restrict__ bias,
    u16* __restrict__ outc, const unsigned* __restrict__ scal,
    int O_total, int sInSlot, int sWSlot, int sOutSlot, unsigned* mslot) {

    constexpr int F = OB / 64;                    // o-fragments per wave (wave covers F*16 o's... F frags of 16)
    __shared__ __align__(16) u16 lds[(DUAL ? 2 : 1) * 64 * K];
    int lane = threadIdx.x & 63, wv = threadIdx.x >> 6;
    int lane15 = lane & 15;
    int b = blockIdx.x >> 8;
    long px0 = (long)(blockIdx.x & 255) * 64;
    long pixbase = (long)b * HW + px0;
    int oB = blockIdx.y * OB;
    int oW = wv * (OB / 4);                       // wave's o-offset within block (OB/4 = F*16)

    for (int s = threadIdx.x; s < 8 * K; s += 256) {        // 64 px * K/8 slots
        int px = s / (K / 8), cs = s % (K / 8);
        long gsrc = (pixbase + px) * K + cs * 8;
        int addr = (px * K * 2 + cs * 16) ^ ((px & 7) << 4);
        *reinterpret_cast<uint4v*>(reinterpret_cast<char*>(lds) + addr) =
            *reinterpret_cast<const uint4v*>(bc0 + gsrc);
        if (DUAL)
            *reinterpret_cast<uint4v*>(reinterpret_cast<char*>(lds) + 64 * K * 2 + addr) =
                *reinterpret_cast<const uint4v*>(bc1 + gsrc);
    }
    __syncthreads();

    const f32x4 z4 = {0.f, 0.f, 0.f, 0.f};
    f32x4 accA[F][4], accB[F][4];
    #pragma unroll
    for (int i = 0; i < F; i++)
        #pragma unroll
        for (int j = 0; j < 4; j++) { accA[i][j] = z4; accB[i][j] = z4; }

    int kk = (lane >> 4) * 8;
    for (int kb = 0; kb < K / 32; kb++) {
        int kbase = kb * 32 + kk;
        short8v a[F];
        #pragma unroll
        for (int f = 0; f < F; f++)
            a[f] = *reinterpret_cast<const short8v*>(wc + (long)(oB + oW + f * 16 + lane15) * K + kbase);
        #pragma unroll
        for (int fn = 0; fn < 4; fn++) {
            int col = fn * 16 + lane15;
            int ad = (col * K * 2 + kbase * 2) ^ ((col & 7) << 4);
            short8v b0 = *reinterpret_cast<const short8v*>(reinterpret_cast<char*>(lds) + ad);
            #pragma unroll
            for (int f = 0; f < F; f++) accA[f][fn] = MFMA16(a[f], b0, accA[f][fn]);
            if (DUAL) {
                short8v b1 = *reinterpret_cast<const short8v*>(
                    reinterpret_cast<char*>(lds) + 64 * K * 2 + ad);
                #pragma unroll
                for (int f = 0; f < F; f++) accB[f][fn] = MFMA16(a[f], b1, accB[f][fn]);
            }
        }
    }

    float sW = ubits(scal[sWSlot]);
    float sA, sB_;
    if (DUAL) {
        float s1 = fmaxf(ubits(scal[3]), EPSQ) / 255.f;
        sA  = fmaxf(255.f * s1, EPSQ) / 127.f;     // == s1b used to make j codes
        sB_ = fmaxf(ubits(scal[2]), EPSQ) / 127.f; // == sx used to make i codes
    } else {
        sA = fmaxf(ubits(scal[sInSlot]), EPSQ) / 255.f;
        sB_ = 0.f;
    }

    if (MODE == 0) {
        float mm = 0.f;
        #pragma unroll
        for (int f = 0; f < F; f++)
        #pragma unroll
        for (int fn = 0; fn < 4; fn++)
        #pragma unroll
        for (int r = 0; r < 4; r++) {
            int o = oB + oW + f * 16 + (lane >> 4) * 4 + r;
            float av = DUAL ? (sA * accA[f][fn][r] + sB_ * accB[f][fn][r])
                            : sA * accA[f][fn][r];
            float v = fmaxf(sW * av + bias[o], 0.f);
            mm = fmaxf(mm, v);
        }
        block_max_atomic2(mm, mslot, reinterpret_cast<float*>(lds));
    } else {
        float sOut = fmaxf(ubits(scal[sOutSlot]), EPSQ) / 255.f;
        __syncthreads();                  // all waves done reading staged tile
        #pragma unroll
        for (int f = 0; f < F; f++)
        #pragma unroll
        for (int fn = 0; fn < 4; fn++) {
            ushort4v pk;
            int orow0 = oW + f * 16 + (lane >> 4) * 4;   // o within block [0, OB)
            #pragma unroll
            for (int r = 0; r < 4; r++) {
                int o = oB + orow0 + r;
                float av = DUAL ? (sA * accA[f][fn][r] + sB_ * accB[f][fn][r])
                                : sA * accA[f][fn][r];
                float v = fmaxf(sW * av + bias[o], 0.f);
                pk[r] = f2bf(fminf(rintf(v / sOut), 255.f));
            }
            int pxl = fn * 16 + lane15;
            int ad = (pxl * (OB * 2) + orow0 * 2) ^ ((pxl & 7) << 4);
            *reinterpret_cast<ushort4v*>(reinterpret_cast<char*>(lds) + ad) = pk;
        }
        __syncthreads();
        constexpr int CH = OB / 8;        // 16B chunks per px row
        for (int s = threadIdx.x; s < 64 * CH; s += 256) {
            int px = s / CH, sl = s % CH;
            uint4v v = *reinterpret_cast<uint4v*>(
                reinterpret_cast<char*>(lds) + ((px * (OB * 2) + sl * 16) ^ ((px & 7) << 4)));
            *reinterpret_cast<uint4v*>(outc + (pixbase + px) * O_total + oB + sl * 8) = v;
        }
    }
}

// ---------------- 3x3 conv 128->256 MFMA over bf16 codes, fp32 NCHW out + max ----------------
// One block computes ALL 256 outputs for its 64-px row segment (4 waves x 64 o each).

__global__ __launch_bounds__(256) void conv3x3_mfma_kernel(
    const u16* __restrict__ xc,   // NHWC codes [B*HW][128]
    const u16* __restrict__ wc,   // [256][9][128] codes
    const float* __restrict__ bias, float* __restrict__ out,
    const unsigned* __restrict__ scal, unsigned* mslot) {

    __shared__ __align__(16) u16 lds[3 * 66 * 128];
    int lane = threadIdx.x & 63, wv = threadIdx.x >> 6;
    int lane15 = lane & 15;
    int bx = blockIdx.x;
    int b = bx >> 8, h = (bx >> 1) & 127, wseg = bx & 1;
    int oW = wv * 64;                      // wave's o-range base (0..192)

    // stage 3 rows x 66 cols x 128 ch (bf16), halo col may be OOB (zero-filled below)
    for (int s = threadIdx.x; s < 3 * 66 * 16; s += 256) {
        int row = s / (66 * 16), rem = s % (66 * 16), col = rem >> 4, sl = rem & 15;
        int hh = h + row - 1;
        if (hh < 0 || hh > 127) continue;      // row never read (tap skipped)
        int wgl = wseg * 64 + col - 1;         // -1..128 possible at edges
        long pix = (long)b * HW + (long)hh * 128 + wgl;
        uint4v v = *reinterpret_cast<const uint4v*>(xc + pix * 128 + sl * 8);
        int addr = ((row * 66 + col) * 256 + sl * 16) ^ ((col & 7) << 4);
        *reinterpret_cast<uint4v*>(reinterpret_cast<char*>(lds) + addr) = v;
    }
    __syncthreads();
    {   // zero the out-of-image halo column
        int col = wseg ? 65 : 0;
        if (threadIdx.x < 48) {
            int row = threadIdx.x >> 4, sl = threadIdx.x & 15;
            int addr = ((row * 66 + col) * 256 + sl * 16) ^ ((col & 7) << 4);
            uint4v z = {0, 0, 0, 0};
            *reinterpret_cast<uint4v*>(reinterpret_cast<char*>(lds) + addr) = z;
        }
    }
    __syncthreads();

    const f32x4 z4 = {0.f, 0.f, 0.f, 0.f};
    f32x4 acc[4][4];
    #pragma unroll
    for (int i = 0; i < 4; i++)
        #pragma unroll
        for (int j = 0; j < 4; j++) acc[i][j] = z4;

    int kk = (lane >> 4) * 8;
    for (int di = 0; di < 3; di++) {
        int hh = h + di - 1;
        if (hh < 0 || hh > 127) continue;      // block-uniform
        for (int dj = 0; dj < 3; dj++) {
            int tap = di * 3 + dj;
            for (int kb = 0; kb < 4; kb++) {
                int kbase = kb * 32 + kk;
                short8v a[4];
                #pragma unroll
                for (int f = 0; f < 4; f++)
                    a[f] = *reinterpret_cast<const short8v*>(
                        wc + ((long)(oW + f * 16 + lane15) * 9 + tap) * 128 + kbase);
                short8v bb[4];
                #pragma unroll
                for (int fn = 0; fn < 4; fn++) {
                    int col = fn * 16 + lane15 + dj;
                    bb[fn] = *reinterpret_cast<const short8v*>(reinterpret_cast<char*>(lds) +
                        (((di * 66 + col) * 256 + kbase * 2) ^ ((col & 7) << 4)));
                }
                #pragma unroll
                for (int f = 0; f < 4; f++)
                    #pragma unroll
                    for (int fn = 0; fn < 4; fn++)
                        acc[f][fn] = MFMA16(a[f], bb[fn], acc[f][fn]);
            }
        }
    }

    float s5 = fmaxf(ubits(scal[5]), EPSQ) / 255.f;
    float sc = ubits(scal[10]) * s5;
    float mm = 0.f;
    #pragma unroll
    for (int f = 0; f < 4; f++)
    #pragma unroll
    for (int fn = 0; fn < 4; fn++)
    #pragma unroll
    for (int r = 0; r < 4; r++) {
        int o  = oW + f * 16 + (lane >> 4) * 4 + r;
        int px = wseg * 64 + fn * 16 + lane15;
        float v = fmaxf(sc * acc[f][fn][r] + bias[o], 0.f);
        mm = fmaxf(mm, v);
        out[((long)(b * CO + o)) * HW + h * 128 + px] = v;
    }
    block_max_atomic2(mm, mslot, reinterpret_cast<float*>(lds));
}

// ---------------- in-place quant of a relu'd tensor (255 levels) ----------------

__global__ void quant_inplace_kernel(float4* __restrict__ p, long n4,
                                     const unsigned* __restrict__ scal, int idx) {
    float s = fmaxf(__uint_as_float(scal[idx]), EPSQ) / 255.f;
    long i0 = (long)blockIdx.x * blockDim.x + threadIdx.x;
    long str = (long)gridDim.x * blockDim.x;
    for (long i = i0; i < n4; i += str) {
        float4 v = p[i];
        v.x = fminf(rintf(v.x / s), 255.f) * s;
        v.y = fminf(rintf(v.y / s), 255.f) * s;
        v.z = fminf(rintf(v.z / s), 255.f) * s;
        v.w = fminf(rintf(v.w / s), 255.f) * s;
        p[i] = v;
    }
}

// ---------------- launch ----------------

extern "C" void kernel_launch(void* const* d_in, const int* in_sizes, int n_in,
                              void* d_out, int out_size, void* d_ws, size_t ws_size,
                              hipStream_t stream) {
    (void)in_sizes; (void)n_in; (void)out_size; (void)ws_size;
    const float* x     = (const float*)d_in[0];
    const float* dw1_w = (const float*)d_in[1];
    const float* dw1_b = (const float*)d_in[2];
    const float* dw2_w = (const float*)d_in[3];
    const float* dw2_b = (const float*)d_in[4];
    const float* pw1_w = (const float*)d_in[5];
    const float* pw1_b = (const float*)d_in[6];
    const float* pw2_w = (const float*)d_in[7];
    const float* pw2_b = (const float*)d_in[8];
    const float* up_w  = (const float*)d_in[9];
    const float* up_b  = (const float*)d_in[10];
    float* out = (float*)d_out;
    float* ws  = (float*)d_ws;

    // ws layout (float units):
    // [0, NX)        Abuf fp32            (later: p1codes low half)
    // [NX, 2NX)      Bbuf fp32            (later: p1codes high half)
    // [2NX, 2NX+NX/2) jcode bf16 NX       (later: p2codes bf16 NX)
    // [2NX+NX/2, 3NX) icode bf16 NX
    // [3NX, ...)     weight area + scal
    float* Abuf = ws;
    float* Bbuf = ws + NX;
    u16*   jcode = (u16*)(ws + 2 * NX);
    u16*   icode = (u16*)(ws + 2 * NX + NX / 2);
    u16*   p1codes = (u16*)ws;              // NP1 bf16 over A+B (exact fit)
    u16*   p2codes = (u16*)(ws + 2 * NX);   // NX bf16 over jcode

    float* wbase   = ws + 3 * NX;
    float* wq_dw1 = wbase;          float* bq_dw1 = wbase + 1152;
    float* wq_dw2 = wbase + 1280;   float* bq_dw2 = wbase + 2432;
    float* bq_pw1 = wbase + 2560;
    float* bq_pw2 = wbase + 3072;
    float* bq_up  = wbase + 3200;
    u16*   wc_pw1 = (u16*)(wbase + 3456);    // 65536 codes -> 32768 floats
    u16*   wc_pw2 = (u16*)(wbase + 36224);   // 65536 codes
    u16*   wc_up  = (u16*)(wbase + 68992);   // 294912 codes -> 147456 floats
    unsigned* scal = (unsigned*)(wbase + 216448);
    // slots: 0 SX | 1 M1(dw1 relu) | 2 MR1(|r1|) | 3 M2(dw2 relu) | 4 M3(pw1 relu)
    //        5 M4(pw2 relu) | 6 M5(up relu) | 8 sW_pw1 | 9 sW_pw2 | 10 sW_up
    //        16..25 raw weight-tensor absmax

    (void)hipMemsetAsync(scal, 0, 32 * sizeof(unsigned), stream);

    QW q0{dw1_w, wq_dw1, nullptr, 1152, 0, 0}, q1{dw1_b, bq_dw1, nullptr, 128, 0, 0},
       q2{dw2_w, wq_dw2, nullptr, 1152, 0, 0}, q3{dw2_b, bq_dw2, nullptr, 128, 0, 0},
       q4{pw1_w, nullptr, wc_pw1, 65536, 1, 8}, q5{pw1_b, bq_pw1, nullptr, 512, 0, 0},
       q6{pw2_w, nullptr, wc_pw2, 65536, 1, 9}, q7{pw2_b, bq_pw2, nullptr, 128, 0, 0},
       q8{up_w, nullptr, wc_up, 294912, 2, 10}, q9{up_b, bq_up, nullptr, 256, 0, 0};
    wabsmax_kernel<<<dim3(32, 10), 256, 0, stream>>>(q0, q1, q2, q3, q4, q5, q6, q7, q8, q9, scal);
    wquant_kernel<<<dim3(32, 10), 256, 0, stream>>>(q0, q1, q2, q3, q4, q5, q6, q7, q8, q9, scal);

    absmax_kernel<<<2048, 256, 0, stream>>>(x, NX, scal + 0);

    // residual block 1 (fp32 path)
    dwconv_kernel<<<dim3(Bn * Cc, Hh / 8), 256, 0, stream>>>(x, wq_dw1, bq_dw1, Abuf, scal + 1);
    residual_kernel<<<4096, 256, 0, stream>>>((const float4*)Abuf, (const float4*)x,
                                              (float4*)Bbuf, scal, 1, 0, scal + 2);
    // residual block 2 -> bf16 NHWC code planes
    dwconv_kernel<<<dim3(Bn * Cc, Hh / 8), 256, 0, stream>>>(Bbuf, wq_dw2, bq_dw2, Abuf, scal + 3);
    residual2_codes_kernel<<<2048, 256, 0, stream>>>(Abuf, Bbuf, jcode, icode, scal);

    // pw1 (dual-plane exact GEMM, 256 o per block): pass1 max -> slot4, pass2 codes -> p1codes
    pwmfma_kernel<128, 256, true, 0><<<dim3(2048, 2), 256, 0, stream>>>(
        jcode, icode, wc_pw1, bq_pw1, nullptr, scal, C4, 0, 8, 0, scal + 4);
    pwmfma_kernel<128, 256, true, 1><<<dim3(2048, 2), 256, 0, stream>>>(
        jcode, icode, wc_pw1, bq_pw1, p1codes, scal, C4, 0, 8, 4, nullptr);

    // pw2 (all 128 o per block): pass1 max -> slot5, pass2 codes -> p2codes
    pwmfma_kernel<512, 128, false, 0><<<dim3(2048, 1), 256, 0, stream>>>(
        p1codes, nullptr, wc_pw2, bq_pw2, nullptr, scal, Cc, 4, 9, 0, scal + 5);
    pwmfma_kernel<512, 128, false, 1><<<dim3(2048, 1), 256, 0, stream>>>(
        p1codes, nullptr, wc_pw2, bq_pw2, p2codes, scal, Cc, 4, 9, 5, nullptr);

    // up 3x3 (all 256 o per block) -> d_out fp32 + max slot6, then final quant in place
    conv3x3_mfma_kernel<<<2048, 256, 0, stream>>>(p2codes, wc_up, bq_up, out, scal, scal + 6);
    quant_inplace_kernel<<<4096, 256, 0, stream>>>((float4*)out, NOUT / 4, scal, 6);
}

// Round 5
// 718.407 us; speedup vs baseline: 7.5724x; 1.1534x over previous
//
#include <hip/hip_runtime.h>

#define EPSQ 1e-8f

typedef unsigned short u16;
typedef __attribute__((ext_vector_type(8))) short short8v;
typedef __attribute__((ext_vector_type(8))) unsigned short ushort8v;
typedef __attribute__((ext_vector_type(4))) unsigned short ushort4v;
typedef __attribute__((ext_vector_type(4))) float f32x4;
typedef __attribute__((ext_vector_type(4))) unsigned int uint4v;

static constexpr int  Bn = 8, Cc = 128, Hh = 128, Ww = 128, HW = Hh * Ww; // 16384
static constexpr int  C4 = 512, CO = 256;
static constexpr long NX   = (long)Bn * Cc * HW;   // 16,777,216
static constexpr long NOUT = (long)Bn * CO * HW;   // 33,554,432

#define MFMA16(a,b,c) __builtin_amdgcn_mfma_f32_16x16x32_bf16(a,b,c,0,0,0)

__device__ __forceinline__ u16 f2bf(float f) { return (u16)(__float_as_uint(f) >> 16); } // exact for small ints
__device__ __forceinline__ float ubits(unsigned u) { return __uint_as_float(u); }

// ---------------- reductions ----------------

__device__ __forceinline__ float block_reduce_max(float v) {
    __shared__ float sm[8];
    #pragma unroll
    for (int off = 32; off; off >>= 1) v = fmaxf(v, __shfl_down(v, off));
    int lane = threadIdx.x & 63, wid = threadIdx.x >> 6;
    int nw = (blockDim.x + 63) >> 6;
    if (lane == 0) sm[wid] = v;
    __syncthreads();
    float r = sm[0];
    for (int i = 1; i < nw; i++) r = fmaxf(r, sm[i]);
    __syncthreads();
    return r;
}

__device__ __forceinline__ void block_max_atomic(float v, unsigned* slot) {
    #pragma unroll
    for (int off = 32; off; off >>= 1) v = fmaxf(v, __shfl_down(v, off));
    __shared__ float sm[8];
    int lane = threadIdx.x & 63, wid = threadIdx.x >> 6;
    if (lane == 0) sm[wid] = v;
    __syncthreads();
    if (threadIdx.x == 0) {
        float m = sm[0];
        int nw = (blockDim.x + 63) >> 6;
        for (int i = 1; i < nw; i++) m = fmaxf(m, sm[i]);
        if (m > __uint_as_float(*(volatile unsigned*)slot))
            atomicMax(slot, __float_as_uint(m));
    }
    __syncthreads();
}

// version with caller-provided LDS scratch (for kernels whose static LDS is large)
__device__ __forceinline__ void block_max_atomic2(float v, unsigned* slot, float* sm) {
    #pragma unroll
    for (int off = 32; off; off >>= 1) v = fmaxf(v, __shfl_down(v, off));
    int lane = threadIdx.x & 63, wid = threadIdx.x >> 6;
    __syncthreads();                       // LDS may be in use by other waves
    if (lane == 0) sm[wid] = v;
    __syncthreads();
    if (threadIdx.x == 0) {
        float m = sm[0];
        int nw = (blockDim.x + 63) >> 6;
        for (int i = 1; i < nw; i++) m = fmaxf(m, sm[i]);
        if (m > __uint_as_float(*(volatile unsigned*)slot))
            atomicMax(slot, __float_as_uint(m));
    }
}

// ---------------- absmax over big tensor ----------------

__global__ void absmax_kernel(const float* __restrict__ x, long n, unsigned* slot) {
    long i = (long)blockIdx.x * blockDim.x + threadIdx.x;
    long stride = (long)gridDim.x * blockDim.x;
    const float4* x4 = (const float4*)x;
    long n4 = n >> 2;
    float m = 0.f;
    for (long j = i; j < n4; j += stride) {
        float4 v = x4[j];
        m = fmaxf(m, fmaxf(fmaxf(fabsf(v.x), fabsf(v.y)), fmaxf(fabsf(v.z), fabsf(v.w))));
    }
    block_max_atomic(m, slot);
}

// ---------------- weight fake-quant (parallel: absmax pass + quantize pass) ----------------
// mode 0: write fp32 dequant to dstF.
// mode 1: write bf16 codes in MFMA-fragment order: [otile][kb][lane][8],
//         lane = q*16 + r, where o = otile*16 + r, k = kb*32 + q*8 + e.
// mode 2: same but 3x3 (K=128, 9 taps): [otile][tap][kb][lane][8].
struct QW { const float* src; float* dstF; u16* dstC; int n; int mode; int slot; int kdim; };

__device__ __forceinline__ QW qw_select(const QW& q0, const QW& q1, const QW& q2, const QW& q3,
                                        const QW& q4, const QW& q5, const QW& q6, const QW& q7,
                                        const QW& q8, const QW& q9, int t) {
    switch (t) {
        case 0: return q0; case 1: return q1; case 2: return q2; case 3: return q3;
        case 4: return q4; case 5: return q5; case 6: return q6; case 7: return q7;
        case 8: return q8; default: return q9;
    }
}

__global__ void wabsmax_kernel(QW q0, QW q1, QW q2, QW q3, QW q4,
                               QW q5, QW q6, QW q7, QW q8, QW q9,
                               unsigned* __restrict__ scal) {
    QW q = qw_select(q0, q1, q2, q3, q4, q5, q6, q7, q8, q9, blockIdx.y);
    int i0 = blockIdx.x * blockDim.x + threadIdx.x;
    int str = gridDim.x * blockDim.x;
    float m = 0.f;
    for (int i = i0; i < q.n; i += str) m = fmaxf(m, fabsf(q.src[i]));
    block_max_atomic(m, scal + 16 + blockIdx.y);
}

__global__ void wquant_kernel(QW q0, QW q1, QW q2, QW q3, QW q4,
                              QW q5, QW q6, QW q7, QW q8, QW q9,
                              unsigned* __restrict__ scal) {
    QW q = qw_select(q0, q1, q2, q3, q4, q5, q6, q7, q8, q9, blockIdx.y);
    float s = fmaxf(ubits(scal[16 + blockIdx.y]), EPSQ) / 127.f;
    if (q.mode != 0 && blockIdx.x == 0 && threadIdx.x == 0) scal[q.slot] = __float_as_uint(s);
    int i0 = blockIdx.x * blockDim.x + threadIdx.x;
    int str = gridDim.x * blockDim.x;
    for (int i = i0; i < q.n; i += str) {
        float v = fminf(fmaxf(rintf(q.src[i] / s), -127.f), 127.f);
        if (q.mode == 0) q.dstF[i] = v * s;
        else if (q.mode == 1) {
            int o = i / q.kdim, k = i % q.kdim;
            int otile = o >> 4, r = o & 15, kb = k >> 5, qq = (k & 31) >> 3, e = k & 7;
            q.dstC[((otile * (q.kdim >> 5) + kb) * 64 + qq * 16 + r) * 8 + e] = f2bf(v);
        } else {
            int o = i / 1152, rem = i % 1152, c = rem / 9, t = rem % 9;
            int otile = o >> 4, r = o & 15, kb = c >> 5, qq = (c & 31) >> 3, e = c & 7;
            q.dstC[(((otile * 9 + t) * 4 + kb) * 64 + qq * 16 + r) * 8 + e] = f2bf(v);
        }
    }
}

// ---------------- depthwise 3x3 (pad 1), fp32 ----------------

__global__ void dwconv_kernel(const float* __restrict__ in, const float* __restrict__ wq,
                              const float* __restrict__ bq, float* __restrict__ out,
                              unsigned* mslot) {
    int bc = blockIdx.x;              // b*C + c
    int c  = bc & (Cc - 1);
    float w[9];
    #pragma unroll
    for (int k = 0; k < 9; k++) w[k] = wq[c * 9 + k];
    float bias = bq[c];
    const float* src = in + (long)bc * HW;
    float* dst = out + (long)bc * HW;
    int j  = threadIdx.x & (Ww - 1);
    int r2 = threadIdx.x >> 7;        // 0..1
    float mm = 0.f;
    #pragma unroll
    for (int rr = 0; rr < 4; rr++) {
        int i = blockIdx.y * 8 + rr * 2 + r2;
        float acc = 0.f;
        #pragma unroll
        for (int di = 0; di < 3; di++) {
            int ii = i + di - 1;
            if (ii < 0 || ii >= Hh) continue;
            #pragma unroll
            for (int dj = 0; dj < 3; dj++) {
                int jj = j + dj - 1;
                if (jj < 0 || jj >= Ww) continue;
                acc = fmaf(w[di * 3 + dj], src[ii * Ww + jj], acc);
            }
        }
        acc += bias;
        dst[i * Ww + j] = acc;
        mm = fmaxf(mm, fmaxf(acc, 0.f));
    }
    block_max_atomic(mm, mslot);
}

// ---------------- residual 1: r = fq(quant_relu(t)) + fq(x), fp32 out + max ----------------

__global__ void residual_kernel(const float4* __restrict__ t, const float4* __restrict__ xin,
                                float4* __restrict__ r, const unsigned* __restrict__ scal,
                                int mReluIdx, int mXIdx, unsigned* mOut) {
    float s1  = fmaxf(__uint_as_float(scal[mReluIdx]), EPSQ) / 255.f;
    float mh  = 255.f * s1;
    float s1b = fmaxf(mh, EPSQ) / 127.f;
    float sx  = fmaxf(__uint_as_float(scal[mXIdx]), EPSQ) / 127.f;
    long i0 = (long)blockIdx.x * blockDim.x + threadIdx.x;
    long str = (long)gridDim.x * blockDim.x;
    long n4 = NX >> 2;
    float mm = 0.f;
    for (long i = i0; i < n4; i += str) {
        float4 tv = t[i];
        float4 xv = xin[i];
        float o[4];
        float tc[4] = {tv.x, tv.y, tv.z, tv.w};
        float xc[4] = {xv.x, xv.y, xv.z, xv.w};
        #pragma unroll
        for (int k = 0; k < 4; k++) {
            float h  = fminf(rintf(fmaxf(tc[k], 0.f) / s1), 255.f) * s1;
            float hq = fminf(fmaxf(rintf(h / s1b), -127.f), 127.f) * s1b;
            float xq = fminf(fmaxf(rintf(xc[k] / sx), -127.f), 127.f) * sx;
            o[k] = hq + xq;
            mm = fmaxf(mm, fabsf(o[k]));
        }
        float4 ov = {o[0], o[1], o[2], o[3]};
        r[i] = ov;
    }
    if (mOut) block_max_atomic(mm, mOut);
}

// ---------------- residual 2: emit NHWC bf16 code planes (j from dw2-path, i from r1) ----------------

__global__ __launch_bounds__(256) void residual2_codes_kernel(
    const float* __restrict__ t2, const float* __restrict__ r1,
    u16* __restrict__ jc, u16* __restrict__ ic, const unsigned* __restrict__ scal) {
    float s1  = fmaxf(ubits(scal[3]), EPSQ) / 255.f;
    float s1b = fmaxf(255.f * s1, EPSQ) / 127.f;
    float sx  = fmaxf(ubits(scal[2]), EPSQ) / 127.f;
    int b = blockIdx.x >> 8;
    long px0 = (long)(blockIdx.x & 255) * 64;
    __shared__ __align__(16) u16 lj[128 * 64];
    __shared__ __align__(16) u16 li[128 * 64];
    int px = threadIdx.x & 63, cq = threadIdx.x >> 6;
    for (int c0 = 0; c0 < 128; c0 += 4) {
        int c = c0 + cq;
        long g = ((long)b * Cc + c) * HW + px0 + px;
        float t = t2[g], x = r1[g];
        float hq = fminf(rintf(fmaxf(t, 0.f) / s1), 255.f) * s1;
        float j = fminf(fmaxf(rintf(hq / s1b), -127.f), 127.f);
        float i = fminf(fmaxf(rintf(x / sx), -127.f), 127.f);
        lj[c * 64 + px] = f2bf(j);
        li[c * 64 + px] = f2bf(i);
    }
    __syncthreads();
    int px2 = threadIdx.x & 63, csq = threadIdx.x >> 6;
    for (int it = 0; it < 4; it++) {
        int cs = it * 4 + csq;        // 0..15
        ushort8v pj, pi;
        #pragma unroll
        for (int k = 0; k < 8; k++) {
            pj[k] = lj[(cs * 8 + k) * 64 + px2];
            pi[k] = li[(cs * 8 + k) * 64 + px2];
        }
        long dst = ((long)b * HW + px0 + px2) * 128 + cs * 8;
        *reinterpret_cast<ushort8v*>(jc + dst) = pj;
        *reinterpret_cast<ushort8v*>(ic + dst) = pi;
    }
}

// ---------------- pointwise MFMA GEMM over bf16 integer codes ----------------
// Block: 256 thr = 4 waves. Tile: OB outputs x 64 px. Wave wv owns o-range wv*(OB/4).
// Weights pre-packed in fragment order: [otile][kb][lane][8] -> coalesced 1KB loads.
// MODE 0: track relu max only. MODE 1: write quantized bf16 codes NHWC.
template<int K, int OB, bool DUAL, int MODE>
__global__ __launch_bounds__(256) void pwmfma_kernel(
    const u16* __restrict__ bc0, const u16* __restrict__ bc1,
    const u16* __restrict__ wc, const float* __restrict__ bias,
    u16* __restrict__ outc, const unsigned* __restrict__ scal,
    int O_total, int sInSlot, int sWSlot, int sOutSlot, unsigned* mslot) {

    constexpr int F = OB / 64;                    // o-fragments (of 16) per wave
    constexpr int KB = K / 32;
    __shared__ __align__(16) u16 lds[(DUAL ? 2 : 1) * 64 * K];
    int lane = threadIdx.x & 63, wv = threadIdx.x >> 6;
    int lane15 = lane & 15;
    int b = blockIdx.x >> 8;
    long px0 = (long)(blockIdx.x & 255) * 64;
    long pixbase = (long)b * HW + px0;
    int oB = blockIdx.y * OB;
    int oW = wv * (OB / 4);                       // wave's o-offset within block

    for (int s = threadIdx.x; s < 8 * K; s += 256) {        // 64 px * K/8 slots
        int px = s / (K / 8), cs = s % (K / 8);
        long gsrc = (pixbase + px) * K + cs * 8;
        int addr = (px * K * 2 + cs * 16) ^ ((px & 7) << 4);
        *reinterpret_cast<uint4v*>(reinterpret_cast<char*>(lds) + addr) =
            *reinterpret_cast<const uint4v*>(bc0 + gsrc);
        if (DUAL)
            *reinterpret_cast<uint4v*>(reinterpret_cast<char*>(lds) + 64 * K * 2 + addr) =
                *reinterpret_cast<const uint4v*>(bc1 + gsrc);
    }
    __syncthreads();

    const f32x4 z4 = {0.f, 0.f, 0.f, 0.f};
    f32x4 accA[F][4], accB[F][4];
    #pragma unroll
    for (int i = 0; i < F; i++)
        #pragma unroll
        for (int j = 0; j < 4; j++) { accA[i][j] = z4; accB[i][j] = z4; }

    // packed weight base for this wave: otile0 = (oB+oW)>>4
    const u16* wpack = wc + ((long)((oB + oW) >> 4) * KB) * 512 + lane * 8;

    for (int kb = 0; kb < KB; kb++) {
        int kbase = kb * 32 + (lane >> 4) * 8;
        short8v a[F];
        #pragma unroll
        for (int f = 0; f < F; f++)
            a[f] = *reinterpret_cast<const short8v*>(wpack + ((long)f * KB + kb) * 512);
        #pragma unroll
        for (int fn = 0; fn < 4; fn++) {
            int col = fn * 16 + lane15;
            int ad = (col * K * 2 + kbase * 2) ^ ((col & 7) << 4);
            short8v b0 = *reinterpret_cast<const short8v*>(reinterpret_cast<char*>(lds) + ad);
            #pragma unroll
            for (int f = 0; f < F; f++) accA[f][fn] = MFMA16(a[f], b0, accA[f][fn]);
            if (DUAL) {
                short8v b1 = *reinterpret_cast<const short8v*>(
                    reinterpret_cast<char*>(lds) + 64 * K * 2 + ad);
                #pragma unroll
                for (int f = 0; f < F; f++) accB[f][fn] = MFMA16(a[f], b1, accB[f][fn]);
            }
        }
    }

    float sW = ubits(scal[sWSlot]);
    float sA, sB_;
    if (DUAL) {
        float s1 = fmaxf(ubits(scal[3]), EPSQ) / 255.f;
        sA  = fmaxf(255.f * s1, EPSQ) / 127.f;     // == s1b used to make j codes
        sB_ = fmaxf(ubits(scal[2]), EPSQ) / 127.f; // == sx used to make i codes
    } else {
        sA = fmaxf(ubits(scal[sInSlot]), EPSQ) / 255.f;
        sB_ = 0.f;
    }

    if (MODE == 0) {
        float mm = 0.f;
        #pragma unroll
        for (int f = 0; f < F; f++)
        #pragma unroll
        for (int fn = 0; fn < 4; fn++)
        #pragma unroll
        for (int r = 0; r < 4; r++) {
            int o = oB + oW + f * 16 + (lane >> 4) * 4 + r;
            float av = DUAL ? (sA * accA[f][fn][r] + sB_ * accB[f][fn][r])
                            : sA * accA[f][fn][r];
            float v = fmaxf(sW * av + bias[o], 0.f);
            mm = fmaxf(mm, v);
        }
        block_max_atomic2(mm, mslot, reinterpret_cast<float*>(lds));
    } else {
        float sOut = fmaxf(ubits(scal[sOutSlot]), EPSQ) / 255.f;
        __syncthreads();                  // all waves done reading staged tile
        #pragma unroll
        for (int f = 0; f < F; f++)
        #pragma unroll
        for (int fn = 0; fn < 4; fn++) {
            ushort4v pk;
            int orow0 = oW + f * 16 + (lane >> 4) * 4;   // o within block [0, OB)
            #pragma unroll
            for (int r = 0; r < 4; r++) {
                int o = oB + orow0 + r;
                float av = DUAL ? (sA * accA[f][fn][r] + sB_ * accB[f][fn][r])
                                : sA * accA[f][fn][r];
                float v = fmaxf(sW * av + bias[o], 0.f);
                pk[r] = f2bf(fminf(rintf(v / sOut), 255.f));
            }
            int pxl = fn * 16 + lane15;
            int ad = (pxl * (OB * 2) + orow0 * 2) ^ ((pxl & 7) << 4);
            *reinterpret_cast<ushort4v*>(reinterpret_cast<char*>(lds) + ad) = pk;
        }
        __syncthreads();
        constexpr int CH = OB / 8;        // 16B chunks per px row
        for (int s = threadIdx.x; s < 64 * CH; s += 256) {
            int px = s / CH, sl = s % CH;
            uint4v v = *reinterpret_cast<uint4v*>(
                reinterpret_cast<char*>(lds) + ((px * (OB * 2) + sl * 16) ^ ((px & 7) << 4)));
            *reinterpret_cast<uint4v*>(outc + (pixbase + px) * O_total + oB + sl * 8) = v;
        }
    }
}

// ---------------- 3x3 conv 128->256 MFMA over bf16 codes, fp32 NCHW out + max ----------------
// One block computes ALL 256 outputs for its 64-px row segment (4 waves x 64 o each).
// Weights pre-packed [otile][tap][kb][lane][8] -> coalesced 1KB loads.

__global__ __launch_bounds__(256) void conv3x3_mfma_kernel(
    const u16* __restrict__ xc,   // NHWC codes [B*HW][128]
    const u16* __restrict__ wc,   // packed [16][9][4][64][8]
    const float* __restrict__ bias, float* __restrict__ out,
    const unsigned* __restrict__ scal, unsigned* mslot) {

    __shared__ __align__(16) u16 lds[3 * 66 * 128];
    int lane = threadIdx.x & 63, wv = threadIdx.x >> 6;
    int lane15 = lane & 15;
    int bx = blockIdx.x;
    int b = bx >> 8, h = (bx >> 1) & 127, wseg = bx & 1;
    int oW = wv * 64;                      // wave's o-range base (0..192)

    // stage 3 rows x 66 cols x 128 ch (bf16), halo col may be OOB (zero-filled below)
    for (int s = threadIdx.x; s < 3 * 66 * 16; s += 256) {
        int row = s / (66 * 16), rem = s % (66 * 16), col = rem >> 4, sl = rem & 15;
        int hh = h + row - 1;
        if (hh < 0 || hh > 127) continue;      // row never read (tap skipped)
        int wgl = wseg * 64 + col - 1;         // -1..128 possible at edges
        long pix = (long)b * HW + (long)hh * 128 + wgl;
        uint4v v = *reinterpret_cast<const uint4v*>(xc + pix * 128 + sl * 8);
        int addr = ((row * 66 + col) * 256 + sl * 16) ^ ((col & 7) << 4);
        *reinterpret_cast<uint4v*>(reinterpret_cast<char*>(lds) + addr) = v;
    }
    __syncthreads();
    {   // zero the out-of-image halo column
        int col = wseg ? 65 : 0;
        if (threadIdx.x < 48) {
            int row = threadIdx.x >> 4, sl = threadIdx.x & 15;
            int addr = ((row * 66 + col) * 256 + sl * 16) ^ ((col & 7) << 4);
            uint4v z = {0, 0, 0, 0};
            *reinterpret_cast<uint4v*>(reinterpret_cast<char*>(lds) + addr) = z;
        }
    }
    __syncthreads();

    const f32x4 z4 = {0.f, 0.f, 0.f, 0.f};
    f32x4 acc[4][4];
    #pragma unroll
    for (int i = 0; i < 4; i++)
        #pragma unroll
        for (int j = 0; j < 4; j++) acc[i][j] = z4;

    int kk = (lane >> 4) * 8;
    const u16* wpack = wc + (long)(wv * 4) * 9 * 4 * 512 + lane * 8;  // otile0 = wv*4
    for (int di = 0; di < 3; di++) {
        int hh = h + di - 1;
        if (hh < 0 || hh > 127) continue;      // block-uniform
        for (int dj = 0; dj < 3; dj++) {
            int tap = di * 3 + dj;
            for (int kb = 0; kb < 4; kb++) {
                int kbase = kb * 32 + kk;
                short8v a[4];
                #pragma unroll
                for (int f = 0; f < 4; f++)
                    a[f] = *reinterpret_cast<const short8v*>(
                        wpack + ((long)(f * 9 + tap) * 4 + kb) * 512);
                short8v bb[4];
                #pragma unroll
                for (int fn = 0; fn < 4; fn++) {
                    int col = fn * 16 + lane15 + dj;
                    bb[fn] = *reinterpret_cast<const short8v*>(reinterpret_cast<char*>(lds) +
                        (((di * 66 + col) * 256 + kbase * 2) ^ ((col & 7) << 4)));
                }
                #pragma unroll
                for (int f = 0; f < 4; f++)
                    #pragma unroll
                    for (int fn = 0; fn < 4; fn++)
                        acc[f][fn] = MFMA16(a[f], bb[fn], acc[f][fn]);
            }
        }
    }

    float s5 = fmaxf(ubits(scal[5]), EPSQ) / 255.f;
    float sc = ubits(scal[10]) * s5;
    float mm = 0.f;
    #pragma unroll
    for (int f = 0; f < 4; f++)
    #pragma unroll
    for (int fn = 0; fn < 4; fn++)
    #pragma unroll
    for (int r = 0; r < 4; r++) {
        int o  = oW + f * 16 + (lane >> 4) * 4 + r;
        int px = wseg * 64 + fn * 16 + lane15;
        float v = fmaxf(sc * acc[f][fn][r] + bias[o], 0.f);
        mm = fmaxf(mm, v);
        out[((long)(b * CO + o)) * HW + h * 128 + px] = v;
    }
    block_max_atomic2(mm, mslot, reinterpret_cast<float*>(lds));
}

// ---------------- in-place quant of a relu'd tensor (255 levels) ----------------

__global__ void quant_inplace_kernel(float4* __restrict__ p, long n4,
                                     const unsigned* __restrict__ scal, int idx) {
    float s = fmaxf(__uint_as_float(scal[idx]), EPSQ) / 255.f;
    long i0 = (long)blockIdx.x * blockDim.x + threadIdx.x;
    long str = (long)gridDim.x * blockDim.x;
    for (long i = i0; i < n4; i += str) {
        float4 v = p[i];
        v.x = fminf(rintf(v.x / s), 255.f) * s;
        v.y = fminf(rintf(v.y / s), 255.f) * s;
        v.z = fminf(rintf(v.z / s), 255.f) * s;
        v.w = fminf(rintf(v.w / s), 255.f) * s;
        p[i] = v;
    }
}

// ---------------- launch ----------------

extern "C" void kernel_launch(void* const* d_in, const int* in_sizes, int n_in,
                              void* d_out, int out_size, void* d_ws, size_t ws_size,
                              hipStream_t stream) {
    (void)in_sizes; (void)n_in; (void)out_size; (void)ws_size;
    const float* x     = (const float*)d_in[0];
    const float* dw1_w = (const float*)d_in[1];
    const float* dw1_b = (const float*)d_in[2];
    const float* dw2_w = (const float*)d_in[3];
    const float* dw2_b = (const float*)d_in[4];
    const float* pw1_w = (const float*)d_in[5];
    const float* pw1_b = (const float*)d_in[6];
    const float* pw2_w = (const float*)d_in[7];
    const float* pw2_b = (const float*)d_in[8];
    const float* up_w  = (const float*)d_in[9];
    const float* up_b  = (const float*)d_in[10];
    float* out = (float*)d_out;
    float* ws  = (float*)d_ws;

    // ws layout (float units):
    // [0, NX)        Abuf fp32            (later: p1codes low half)
    // [NX, 2NX)      Bbuf fp32            (later: p1codes high half)
    // [2NX, 2NX+NX/2) jcode bf16 NX       (later: p2codes bf16 NX)
    // [2NX+NX/2, 3NX) icode bf16 NX
    // [3NX, ...)     weight area + scal
    float* Abuf = ws;
    float* Bbuf = ws + NX;
    u16*   jcode = (u16*)(ws + 2 * NX);
    u16*   icode = (u16*)(ws + 2 * NX + NX / 2);
    u16*   p1codes = (u16*)ws;              // NP1 bf16 over A+B (exact fit)
    u16*   p2codes = (u16*)(ws + 2 * NX);   // NX bf16 over jcode

    float* wbase   = ws + 3 * NX;
    float* wq_dw1 = wbase;          float* bq_dw1 = wbase + 1152;
    float* wq_dw2 = wbase + 1280;   float* bq_dw2 = wbase + 2432;
    float* bq_pw1 = wbase + 2560;
    float* bq_pw2 = wbase + 3072;
    float* bq_up  = wbase + 3200;
    u16*   wc_pw1 = (u16*)(wbase + 3456);    // 65536 codes -> 32768 floats
    u16*   wc_pw2 = (u16*)(wbase + 36224);   // 65536 codes
    u16*   wc_up  = (u16*)(wbase + 68992);   // 294912 codes -> 147456 floats
    unsigned* scal = (unsigned*)(wbase + 216448);
    // slots: 0 SX | 1 M1(dw1 relu) | 2 MR1(|r1|) | 3 M2(dw2 relu) | 4 M3(pw1 relu)
    //        5 M4(pw2 relu) | 6 M5(up relu) | 8 sW_pw1 | 9 sW_pw2 | 10 sW_up
    //        16..25 raw weight-tensor absmax

    (void)hipMemsetAsync(scal, 0, 32 * sizeof(unsigned), stream);

    QW q0{dw1_w, wq_dw1, nullptr, 1152, 0, 0, 9},  q1{dw1_b, bq_dw1, nullptr, 128, 0, 0, 1},
       q2{dw2_w, wq_dw2, nullptr, 1152, 0, 0, 9},  q3{dw2_b, bq_dw2, nullptr, 128, 0, 0, 1},
       q4{pw1_w, nullptr, wc_pw1, 65536, 1, 8, 128}, q5{pw1_b, bq_pw1, nullptr, 512, 0, 0, 1},
       q6{pw2_w, nullptr, wc_pw2, 65536, 1, 9, 512}, q7{pw2_b, bq_pw2, nullptr, 128, 0, 0, 1},
       q8{up_w, nullptr, wc_up, 294912, 2, 10, 128}, q9{up_b, bq_up, nullptr, 256, 0, 0, 1};
    wabsmax_kernel<<<dim3(32, 10), 256, 0, stream>>>(q0, q1, q2, q3, q4, q5, q6, q7, q8, q9, scal);
    wquant_kernel<<<dim3(32, 10), 256, 0, stream>>>(q0, q1, q2, q3, q4, q5, q6, q7, q8, q9, scal);

    absmax_kernel<<<2048, 256, 0, stream>>>(x, NX, scal + 0);

    // residual block 1 (fp32 path)
    dwconv_kernel<<<dim3(Bn * Cc, Hh / 8), 256, 0, stream>>>(x, wq_dw1, bq_dw1, Abuf, scal + 1);
    residual_kernel<<<4096, 256, 0, stream>>>((const float4*)Abuf, (const float4*)x,
                                              (float4*)Bbuf, scal, 1, 0, scal + 2);
    // residual block 2 -> bf16 NHWC code planes
    dwconv_kernel<<<dim3(Bn * Cc, Hh / 8), 256, 0, stream>>>(Bbuf, wq_dw2, bq_dw2, Abuf, scal + 3);
    residual2_codes_kernel<<<2048, 256, 0, stream>>>(Abuf, Bbuf, jcode, icode, scal);

    // pw1 (dual-plane exact GEMM, 256 o per block): pass1 max -> slot4, pass2 codes -> p1codes
    pwmfma_kernel<128, 256, true, 0><<<dim3(2048, 2), 256, 0, stream>>>(
        jcode, icode, wc_pw1, bq_pw1, nullptr, scal, C4, 0, 8, 0, scal + 4);
    pwmfma_kernel<128, 256, true, 1><<<dim3(2048, 2), 256, 0, stream>>>(
        jcode, icode, wc_pw1, bq_pw1, p1codes, scal, C4, 0, 8, 4, nullptr);

    // pw2 (all 128 o per block): pass1 max -> slot5, pass2 codes -> p2codes
    pwmfma_kernel<512, 128, false, 0><<<dim3(2048, 1), 256, 0, stream>>>(
        p1codes, nullptr, wc_pw2, bq_pw2, nullptr, scal, Cc, 4, 9, 0, scal + 5);
    pwmfma_kernel<512, 128, false, 1><<<dim3(2048, 1), 256, 0, stream>>>(
        p1codes, nullptr, wc_pw2, bq_pw2, p2codes, scal, Cc, 4, 9, 5, nullptr);

    // up 3x3 (all 256 o per block) -> d_out fp32 + max slot6, then final quant in place
    conv3x3_mfma_kernel<<<2048, 256, 0, stream>>>(p2codes, wc_up, bq_up, out, scal, scal + 6);
    quant_inplace_kernel<<<4096, 256, 0, stream>>>((float4*)out, NOUT / 4, scal, 6);
}